// Round 1
// baseline (5279.186 us; speedup 1.0000x reference)
//
#include <hip/hip_runtime.h>

#define NN 100000
#define NE 1600000
#define BN_EPS 1e-5f

static inline int divup(int a, int b) { return (a + b - 1) / b; }

// ---------------- preprocessing ----------------

__global__ void hist_kernel(const int* __restrict__ dst, int* __restrict__ deg, int e) {
    int i = blockIdx.x * blockDim.x + threadIdx.x;
    if (i < e) atomicAdd(&deg[dst[i]], 1);
}

// single-block exclusive scan over deg[0..n) -> row_ptr[0..n]
__global__ void scan_kernel(const int* __restrict__ deg, int* __restrict__ row_ptr, int n) {
    __shared__ int part[1024];
    int t = threadIdx.x;
    int chunk = (n + 1023) / 1024;
    int b0 = t * chunk;
    int b1 = min(b0 + chunk, n);
    int s = 0;
    for (int i = b0; i < b1; ++i) s += deg[i];
    part[t] = s;
    __syncthreads();
    // Hillis-Steele inclusive scan
    for (int off = 1; off < 1024; off <<= 1) {
        int v = (t >= off) ? part[t - off] : 0;
        __syncthreads();
        part[t] += v;
        __syncthreads();
    }
    int run = (t == 0) ? 0 : part[t - 1];
    for (int i = b0; i < b1; ++i) { row_ptr[i] = run; run += deg[i]; }
    if (t == 1023) row_ptr[n] = part[1023];
}

__global__ void dinv_kernel(const int* __restrict__ deg, float* __restrict__ dinv, int n) {
    int i = blockIdx.x * blockDim.x + threadIdx.x;
    if (i < n) {
        int d = deg[i];
        dinv[i] = (d > 0) ? rsqrtf((float)d) : 0.f;
    }
}

__global__ void scatter_kernel(const int* __restrict__ src, const int* __restrict__ dst,
                               const int* __restrict__ row_ptr, int* __restrict__ cursor,
                               const float* __restrict__ dinv,
                               int* __restrict__ col, float* __restrict__ wv, int e) {
    int i = blockIdx.x * blockDim.x + threadIdx.x;
    if (i >= e) return;
    int s = src[i], d = dst[i];
    int pos = row_ptr[d] + atomicAdd(&cursor[d], 1);
    col[pos] = s;
    wv[pos] = -dinv[s] * dinv[d];
}

// ---------------- propagation ----------------
// out[n,f] = sum_e w[e]*feat[col[e],f]        (scale2 == 0)
// out[n,f] = 2*that - prev[n,f]               (scale2 == 1; out may alias prev)
__global__ void prop_kernel(const float* __restrict__ feat, const float* prev,
                            float* out,
                            const int* __restrict__ row_ptr, const int* __restrict__ col,
                            const float* __restrict__ wv, int n, int dim, int scale2) {
    int idx = blockIdx.x * blockDim.x + threadIdx.x;
    if (idx >= n * dim) return;
    int nn = idx / dim;
    int f = idx - nn * dim;
    int e0 = row_ptr[nn], e1 = row_ptr[nn + 1];
    float acc = 0.f;
    for (int e = e0; e < e1; ++e)
        acc = fmaf(wv[e], feat[col[e] * dim + f], acc);
    out[idx] = scale2 ? fmaf(2.f, acc, -prev[idx]) : acc;
}

// ---------------- dense layer accumulate ----------------
// out[n,o] (+)= X[n,:] @ W[:,o]  ; first: init with bias ; bnrelu: fused BN(eval)+ReLU
__global__ void gemm_kernel(const float* __restrict__ X, const float* __restrict__ W,
                            const float* __restrict__ bias, float* __restrict__ out,
                            int n, int din, int dout, int first, int bnrelu,
                            const float* __restrict__ bn_g, const float* __restrict__ bn_b,
                            const float* __restrict__ bn_m, const float* __restrict__ bn_v) {
    int idx = blockIdx.x * blockDim.x + threadIdx.x;
    if (idx >= n * dout) return;
    int nn = idx / dout;
    int o = idx - nn * dout;
    float acc = first ? bias[o] : out[idx];
    const float* xr = X + nn * din;
#pragma unroll 4
    for (int d = 0; d < din; ++d)
        acc = fmaf(xr[d], W[d * dout + o], acc);
    if (bnrelu) {
        float sc = bn_g[o] * rsqrtf(bn_v[o] + BN_EPS);
        acc = fmaf(acc - bn_m[o], sc, bn_b[o]);
        acc = fmaxf(acc, 0.f);
    }
    out[idx] = acc;
}

// ---------------- host driver ----------------

extern "C" void kernel_launch(void* const* d_in, const int* in_sizes, int n_in,
                              void* d_out, int out_size, void* d_ws, size_t ws_size,
                              hipStream_t stream) {
    const float* x  = (const float*)d_in[0];
    const int*   ei = (const int*)d_in[1];   // [2, NE]: src = ei[0..NE), dst = ei[NE..2NE)
    const float* Wl[4] = {(const float*)d_in[2], (const float*)d_in[4],
                          (const float*)d_in[6], (const float*)d_in[8]};
    const float* bl[4] = {(const float*)d_in[3], (const float*)d_in[5],
                          (const float*)d_in[7], (const float*)d_in[9]};
    const float* bn[3][4];
    for (int l = 0; l < 3; ++l)
        for (int j = 0; j < 4; ++j)
            bn[l][j] = (const float*)d_in[10 + 4 * l + j];

    // workspace carve
    char* ws = (char*)d_ws;
    auto alloc = [&](size_t bytes) -> void* {
        void* p = (void*)ws;
        ws += (bytes + 255) & ~(size_t)255;
        return p;
    };
    int*   deg     = (int*)alloc(NN * 4);
    int*   row_ptr = (int*)alloc((NN + 1) * 4);
    int*   cursor  = (int*)alloc(NN * 4);
    float* dinv    = (float*)alloc(NN * 4);
    int*   col     = (int*)alloc(NE * 4);
    float* wv      = (float*)alloc(NE * 4);
    float* P       = (float*)alloc((size_t)NN * 128 * 4);
    float* Q       = (float*)alloc((size_t)NN * 128 * 4);
    float* H1      = (float*)alloc((size_t)NN * 64 * 4);
    float* H2      = (float*)alloc((size_t)NN * 18 * 4);
    float* H3      = (float*)alloc((size_t)NN * 9 * 4);

    const int* srcp = ei;
    const int* dstp = ei + NE;

    hipMemsetAsync(deg, 0, NN * 4, stream);
    hipMemsetAsync(cursor, 0, NN * 4, stream);
    hist_kernel<<<divup(NE, 256), 256, 0, stream>>>(dstp, deg, NE);
    scan_kernel<<<1, 1024, 0, stream>>>(deg, row_ptr, NN);
    dinv_kernel<<<divup(NN, 256), 256, 0, stream>>>(deg, dinv, NN);
    scatter_kernel<<<divup(NE, 256), 256, 0, stream>>>(srcp, dstp, row_ptr, cursor, dinv,
                                                       col, wv, NE);

    auto run_layer = [&](const float* xin, int din, int dout, int K,
                         const float* W, const float* b, float* outl,
                         const float* g, const float* bb, const float* m, const float* v) {
        int gt = NN * dout;            // gemm threads
        int pt = NN * din;             // prop threads
        int gblk = divup(gt, 256);
        int pblk = divup(pt, 256);
        int last = K - 1;
        // k = 0 : out = x @ W0 + b
        gemm_kernel<<<gblk, 256, 0, stream>>>(xin, W, b, outl, NN, din, dout, 1,
                                              (last == 0 && g) ? 1 : 0, g, bb, m, v);
        if (K < 2) return;
        // k = 1 : Tx1 = prop(x); out += Tx1 @ W1
        prop_kernel<<<pblk, 256, 0, stream>>>(xin, nullptr, Q, row_ptr, col, wv, NN, din, 0);
        gemm_kernel<<<gblk, 256, 0, stream>>>(Q, W + (size_t)din * dout, nullptr, outl,
                                              NN, din, dout, 0,
                                              (last == 1 && g) ? 1 : 0, g, bb, m, v);
        const float* t0 = xin;
        float* t1 = Q;
        for (int k = 2; k < K; ++k) {
            // Tx2 = 2*prop(Tx1) - Tx0 ; written in place over Tx0's buffer (except k=2)
            float* t2 = (t0 == xin) ? P : (float*)t0;
            prop_kernel<<<pblk, 256, 0, stream>>>(t1, t0, t2, row_ptr, col, wv, NN, din, 1);
            gemm_kernel<<<gblk, 256, 0, stream>>>(t2, W + (size_t)k * din * dout, nullptr, outl,
                                                  NN, din, dout, 0,
                                                  (last == k && g) ? 1 : 0, g, bb, m, v);
            t0 = t1;
            t1 = t2;
        }
    };

    run_layer(x,  128, 64, 8, Wl[0], bl[0], H1, bn[0][0], bn[0][1], bn[0][2], bn[0][3]);
    run_layer(H1,  64, 18, 6, Wl[1], bl[1], H2, bn[1][0], bn[1][1], bn[1][2], bn[1][3]);
    run_layer(H2,  18,  9, 4, Wl[2], bl[2], H3, bn[2][0], bn[2][1], bn[2][2], bn[2][3]);
    run_layer(H3,   9, 10, 4, Wl[3], bl[3], (float*)d_out, nullptr, nullptr, nullptr, nullptr);
}

// Round 2
// 3580.626 us; speedup vs baseline: 1.4744x; 1.4744x over previous
//
#include <hip/hip_runtime.h>

#define NN 100000
#define NE 1600000
#define BN_EPS 1e-5f

static inline int divup(int a, int b) { return (a + b - 1) / b; }

// ---------------- preprocessing ----------------

__global__ void hist_kernel(const int* __restrict__ dst, int* __restrict__ deg, int e) {
    int i = blockIdx.x * blockDim.x + threadIdx.x;
    if (i < e) atomicAdd(&deg[dst[i]], 1);
}

// single-block exclusive scan over deg[0..n) -> row_ptr[0..n]
__global__ void scan_kernel(const int* __restrict__ deg, int* __restrict__ row_ptr, int n) {
    __shared__ int part[1024];
    int t = threadIdx.x;
    int chunk = (n + 1023) / 1024;
    int b0 = t * chunk;
    int b1 = min(b0 + chunk, n);
    int s = 0;
    for (int i = b0; i < b1; ++i) s += deg[i];
    part[t] = s;
    __syncthreads();
    for (int off = 1; off < 1024; off <<= 1) {
        int v = (t >= off) ? part[t - off] : 0;
        __syncthreads();
        part[t] += v;
        __syncthreads();
    }
    int run = (t == 0) ? 0 : part[t - 1];
    for (int i = b0; i < b1; ++i) { row_ptr[i] = run; run += deg[i]; }
    if (t == 1023) row_ptr[n] = part[1023];
}

__global__ void dinv_kernel(const int* __restrict__ deg, float* __restrict__ dinv, int n) {
    int i = blockIdx.x * blockDim.x + threadIdx.x;
    if (i < n) {
        int d = deg[i];
        dinv[i] = (d > 0) ? rsqrtf((float)d) : 0.f;
    }
}

__global__ void scatter_kernel(const int* __restrict__ src, const int* __restrict__ dst,
                               const int* __restrict__ row_ptr, int* __restrict__ cursor,
                               const float* __restrict__ dinv,
                               int* __restrict__ col, float* __restrict__ wv, int e) {
    int i = blockIdx.x * blockDim.x + threadIdx.x;
    if (i >= e) return;
    int s = src[i], d = dst[i];
    int pos = row_ptr[d] + atomicAdd(&cursor[d], 1);
    col[pos] = s;
    wv[pos] = -dinv[s] * dinv[d];
}

// ---------------- propagation (float4, dim % 4 == 0) ----------------
// 4-way edge unroll, 4 independent accumulators -> >=4 outstanding gathers.
__global__ void prop4_kernel(const float4* __restrict__ feat, const float4* prev,
                             float4* out,
                             const int* __restrict__ row_ptr, const int* __restrict__ col,
                             const float* __restrict__ wv, int n, int dim4, int scale2) {
    int idx = blockIdx.x * blockDim.x + threadIdx.x;
    if (idx >= n * dim4) return;
    int nn = idx / dim4;
    int f = idx - nn * dim4;
    int e0 = row_ptr[nn], e1 = row_ptr[nn + 1];
    float4 a0 = {0.f, 0.f, 0.f, 0.f}, a1 = a0, a2 = a0, a3 = a0;
    int e = e0;
    for (; e + 4 <= e1; e += 4) {
        int c0 = col[e], c1 = col[e + 1], c2 = col[e + 2], c3 = col[e + 3];
        float w0 = wv[e], w1 = wv[e + 1], w2 = wv[e + 2], w3 = wv[e + 3];
        float4 v0 = feat[(size_t)c0 * dim4 + f];
        float4 v1 = feat[(size_t)c1 * dim4 + f];
        float4 v2 = feat[(size_t)c2 * dim4 + f];
        float4 v3 = feat[(size_t)c3 * dim4 + f];
        a0.x = fmaf(w0, v0.x, a0.x); a0.y = fmaf(w0, v0.y, a0.y);
        a0.z = fmaf(w0, v0.z, a0.z); a0.w = fmaf(w0, v0.w, a0.w);
        a1.x = fmaf(w1, v1.x, a1.x); a1.y = fmaf(w1, v1.y, a1.y);
        a1.z = fmaf(w1, v1.z, a1.z); a1.w = fmaf(w1, v1.w, a1.w);
        a2.x = fmaf(w2, v2.x, a2.x); a2.y = fmaf(w2, v2.y, a2.y);
        a2.z = fmaf(w2, v2.z, a2.z); a2.w = fmaf(w2, v2.w, a2.w);
        a3.x = fmaf(w3, v3.x, a3.x); a3.y = fmaf(w3, v3.y, a3.y);
        a3.z = fmaf(w3, v3.z, a3.z); a3.w = fmaf(w3, v3.w, a3.w);
    }
    for (; e < e1; ++e) {
        int c = col[e]; float w = wv[e];
        float4 v = feat[(size_t)c * dim4 + f];
        a0.x = fmaf(w, v.x, a0.x); a0.y = fmaf(w, v.y, a0.y);
        a0.z = fmaf(w, v.z, a0.z); a0.w = fmaf(w, v.w, a0.w);
    }
    float4 acc;
    acc.x = (a0.x + a1.x) + (a2.x + a3.x);
    acc.y = (a0.y + a1.y) + (a2.y + a3.y);
    acc.z = (a0.z + a1.z) + (a2.z + a3.z);
    acc.w = (a0.w + a1.w) + (a2.w + a3.w);
    if (scale2) {
        float4 p = prev[idx];
        acc.x = fmaf(2.f, acc.x, -p.x); acc.y = fmaf(2.f, acc.y, -p.y);
        acc.z = fmaf(2.f, acc.z, -p.z); acc.w = fmaf(2.f, acc.w, -p.w);
    }
    out[idx] = acc;
}

// ---------------- propagation (scalar, any dim) ----------------
__global__ void prop_kernel(const float* __restrict__ feat, const float* prev,
                            float* out,
                            const int* __restrict__ row_ptr, const int* __restrict__ col,
                            const float* __restrict__ wv, int n, int dim, int scale2) {
    int idx = blockIdx.x * blockDim.x + threadIdx.x;
    if (idx >= n * dim) return;
    int nn = idx / dim;
    int f = idx - nn * dim;
    int e0 = row_ptr[nn], e1 = row_ptr[nn + 1];
    float a0 = 0.f, a1 = 0.f, a2 = 0.f, a3 = 0.f;
    int e = e0;
    for (; e + 4 <= e1; e += 4) {
        int c0 = col[e], c1 = col[e + 1], c2 = col[e + 2], c3 = col[e + 3];
        float w0 = wv[e], w1 = wv[e + 1], w2 = wv[e + 2], w3 = wv[e + 3];
        float v0 = feat[(size_t)c0 * dim + f];
        float v1 = feat[(size_t)c1 * dim + f];
        float v2 = feat[(size_t)c2 * dim + f];
        float v3 = feat[(size_t)c3 * dim + f];
        a0 = fmaf(w0, v0, a0); a1 = fmaf(w1, v1, a1);
        a2 = fmaf(w2, v2, a2); a3 = fmaf(w3, v3, a3);
    }
    for (; e < e1; ++e)
        a0 = fmaf(wv[e], feat[(size_t)col[e] * dim + f], a0);
    float acc = (a0 + a1) + (a2 + a3);
    out[idx] = scale2 ? fmaf(2.f, acc, -prev[idx]) : acc;
}

// ---------------- dense layer accumulate ----------------
__global__ void gemm_kernel(const float* __restrict__ X, const float* __restrict__ W,
                            const float* __restrict__ bias, float* __restrict__ out,
                            int n, int din, int dout, int first, int bnrelu,
                            const float* __restrict__ bn_g, const float* __restrict__ bn_b,
                            const float* __restrict__ bn_m, const float* __restrict__ bn_v) {
    int idx = blockIdx.x * blockDim.x + threadIdx.x;
    if (idx >= n * dout) return;
    int nn = idx / dout;
    int o = idx - nn * dout;
    float acc = first ? bias[o] : out[idx];
    const float* xr = X + (size_t)nn * din;
#pragma unroll 4
    for (int d = 0; d < din; ++d)
        acc = fmaf(xr[d], W[d * dout + o], acc);
    if (bnrelu) {
        float sc = bn_g[o] * rsqrtf(bn_v[o] + BN_EPS);
        acc = fmaf(acc - bn_m[o], sc, bn_b[o]);
        acc = fmaxf(acc, 0.f);
    }
    out[idx] = acc;
}

// ---------------- host driver ----------------

extern "C" void kernel_launch(void* const* d_in, const int* in_sizes, int n_in,
                              void* d_out, int out_size, void* d_ws, size_t ws_size,
                              hipStream_t stream) {
    const float* x  = (const float*)d_in[0];
    const int*   ei = (const int*)d_in[1];
    const float* Wl[4] = {(const float*)d_in[2], (const float*)d_in[4],
                          (const float*)d_in[6], (const float*)d_in[8]};
    const float* bl[4] = {(const float*)d_in[3], (const float*)d_in[5],
                          (const float*)d_in[7], (const float*)d_in[9]};
    const float* bn[3][4];
    for (int l = 0; l < 3; ++l)
        for (int j = 0; j < 4; ++j)
            bn[l][j] = (const float*)d_in[10 + 4 * l + j];

    char* ws = (char*)d_ws;
    auto alloc = [&](size_t bytes) -> void* {
        void* p = (void*)ws;
        ws += (bytes + 255) & ~(size_t)255;
        return p;
    };
    int*   deg     = (int*)alloc(NN * 4);
    int*   row_ptr = (int*)alloc((NN + 1) * 4);
    int*   cursor  = (int*)alloc(NN * 4);
    float* dinv    = (float*)alloc(NN * 4);
    int*   col     = (int*)alloc(NE * 4);
    float* wv      = (float*)alloc(NE * 4);
    float* P       = (float*)alloc((size_t)NN * 128 * 4);
    float* Q       = (float*)alloc((size_t)NN * 128 * 4);
    float* H1      = (float*)alloc((size_t)NN * 64 * 4);
    float* H2      = (float*)alloc((size_t)NN * 18 * 4);
    float* H3      = (float*)alloc((size_t)NN * 9 * 4);

    const int* srcp = ei;
    const int* dstp = ei + NE;

    hipMemsetAsync(deg, 0, NN * 4, stream);
    hipMemsetAsync(cursor, 0, NN * 4, stream);
    hist_kernel<<<divup(NE, 256), 256, 0, stream>>>(dstp, deg, NE);
    scan_kernel<<<1, 1024, 0, stream>>>(deg, row_ptr, NN);
    dinv_kernel<<<divup(NN, 256), 256, 0, stream>>>(deg, dinv, NN);
    scatter_kernel<<<divup(NE, 256), 256, 0, stream>>>(srcp, dstp, row_ptr, cursor, dinv,
                                                       col, wv, NE);

    auto prop = [&](const float* feat, const float* prev, float* out, int dim, int scale2) {
        if ((dim & 3) == 0) {
            int dim4 = dim >> 2;
            int pt = NN * dim4;
            prop4_kernel<<<divup(pt, 256), 256, 0, stream>>>(
                (const float4*)feat, (const float4*)prev, (float4*)out,
                row_ptr, col, wv, NN, dim4, scale2);
        } else {
            int pt = NN * dim;
            prop_kernel<<<divup(pt, 256), 256, 0, stream>>>(
                feat, prev, out, row_ptr, col, wv, NN, dim, scale2);
        }
    };

    auto run_layer = [&](const float* xin, int din, int dout, int K,
                         const float* W, const float* b, float* outl,
                         const float* g, const float* bb, const float* m, const float* v) {
        int gt = NN * dout;
        int gblk = divup(gt, 256);
        int last = K - 1;
        gemm_kernel<<<gblk, 256, 0, stream>>>(xin, W, b, outl, NN, din, dout, 1,
                                              (last == 0 && g) ? 1 : 0, g, bb, m, v);
        if (K < 2) return;
        prop(xin, nullptr, Q, din, 0);
        gemm_kernel<<<gblk, 256, 0, stream>>>(Q, W + (size_t)din * dout, nullptr, outl,
                                              NN, din, dout, 0,
                                              (last == 1 && g) ? 1 : 0, g, bb, m, v);
        const float* t0 = xin;
        float* t1 = Q;
        for (int k = 2; k < K; ++k) {
            float* t2 = (t0 == xin) ? P : (float*)t0;
            prop(t1, t0, t2, din, 1);
            gemm_kernel<<<gblk, 256, 0, stream>>>(t2, W + (size_t)k * din * dout, nullptr, outl,
                                                  NN, din, dout, 0,
                                                  (last == k && g) ? 1 : 0, g, bb, m, v);
            t0 = t1;
            t1 = t2;
        }
    };

    run_layer(x,  128, 64, 8, Wl[0], bl[0], H1, bn[0][0], bn[0][1], bn[0][2], bn[0][3]);
    run_layer(H1,  64, 18, 6, Wl[1], bl[1], H2, bn[1][0], bn[1][1], bn[1][2], bn[1][3]);
    run_layer(H2,  18,  9, 4, Wl[2], bl[2], H3, bn[2][0], bn[2][1], bn[2][2], bn[2][3]);
    run_layer(H3,   9, 10, 4, Wl[3], bl[3], (float*)d_out, nullptr, nullptr, nullptr, nullptr);
}

// Round 3
// 2434.756 us; speedup vs baseline: 2.1683x; 1.4706x over previous
//
#include <hip/hip_runtime.h>

#define NN 100000
#define NE 1600000
#define BN_EPS 1e-5f

static inline int divup(int a, int b) { return (a + b - 1) / b; }

// ---------------- preprocessing ----------------

__global__ void hist_kernel(const int* __restrict__ dst, int* __restrict__ deg, int e) {
    int i = blockIdx.x * blockDim.x + threadIdx.x;
    if (i < e) atomicAdd(&deg[dst[i]], 1);
}

__global__ void scan_kernel(const int* __restrict__ deg, int* __restrict__ row_ptr, int n) {
    __shared__ int part[1024];
    int t = threadIdx.x;
    int chunk = (n + 1023) / 1024;
    int b0 = t * chunk;
    int b1 = min(b0 + chunk, n);
    int s = 0;
    for (int i = b0; i < b1; ++i) s += deg[i];
    part[t] = s;
    __syncthreads();
    for (int off = 1; off < 1024; off <<= 1) {
        int v = (t >= off) ? part[t - off] : 0;
        __syncthreads();
        part[t] += v;
        __syncthreads();
    }
    int run = (t == 0) ? 0 : part[t - 1];
    for (int i = b0; i < b1; ++i) { row_ptr[i] = run; run += deg[i]; }
    if (t == 1023) row_ptr[n] = part[1023];
}

__global__ void dinv_kernel(const int* __restrict__ deg, float* __restrict__ dinv, int n) {
    int i = blockIdx.x * blockDim.x + threadIdx.x;
    if (i < n) {
        int d = deg[i];
        dinv[i] = (d > 0) ? rsqrtf((float)d) : 0.f;
    }
}

__global__ void scatter_kernel(const int* __restrict__ src, const int* __restrict__ dst,
                               const int* __restrict__ row_ptr, int* __restrict__ cursor,
                               const float* __restrict__ dinv,
                               int* __restrict__ col, float* __restrict__ wv, int e) {
    int i = blockIdx.x * blockDim.x + threadIdx.x;
    if (i >= e) return;
    int s = src[i], d = dst[i];
    int pos = row_ptr[d] + atomicAdd(&cursor[d], 1);
    col[pos] = s;
    wv[pos] = -dinv[s] * dinv[d];
}

// ---------------- propagation (float4, dim % 4 == 0) ----------------
__global__ void prop4_kernel(const float4* __restrict__ feat, const float4* prev,
                             float4* out,
                             const int* __restrict__ row_ptr, const int* __restrict__ col,
                             const float* __restrict__ wv, int n, int dim4, int scale2) {
    int idx = blockIdx.x * blockDim.x + threadIdx.x;
    if (idx >= n * dim4) return;
    int nn = idx / dim4;
    int f = idx - nn * dim4;
    int e0 = row_ptr[nn], e1 = row_ptr[nn + 1];
    float4 a0 = {0.f, 0.f, 0.f, 0.f}, a1 = a0, a2 = a0, a3 = a0;
    int e = e0;
    for (; e + 4 <= e1; e += 4) {
        int c0 = col[e], c1 = col[e + 1], c2 = col[e + 2], c3 = col[e + 3];
        float w0 = wv[e], w1 = wv[e + 1], w2 = wv[e + 2], w3 = wv[e + 3];
        float4 v0 = feat[(size_t)c0 * dim4 + f];
        float4 v1 = feat[(size_t)c1 * dim4 + f];
        float4 v2 = feat[(size_t)c2 * dim4 + f];
        float4 v3 = feat[(size_t)c3 * dim4 + f];
        a0.x = fmaf(w0, v0.x, a0.x); a0.y = fmaf(w0, v0.y, a0.y);
        a0.z = fmaf(w0, v0.z, a0.z); a0.w = fmaf(w0, v0.w, a0.w);
        a1.x = fmaf(w1, v1.x, a1.x); a1.y = fmaf(w1, v1.y, a1.y);
        a1.z = fmaf(w1, v1.z, a1.z); a1.w = fmaf(w1, v1.w, a1.w);
        a2.x = fmaf(w2, v2.x, a2.x); a2.y = fmaf(w2, v2.y, a2.y);
        a2.z = fmaf(w2, v2.z, a2.z); a2.w = fmaf(w2, v2.w, a2.w);
        a3.x = fmaf(w3, v3.x, a3.x); a3.y = fmaf(w3, v3.y, a3.y);
        a3.z = fmaf(w3, v3.z, a3.z); a3.w = fmaf(w3, v3.w, a3.w);
    }
    for (; e < e1; ++e) {
        int c = col[e]; float w = wv[e];
        float4 v = feat[(size_t)c * dim4 + f];
        a0.x = fmaf(w, v.x, a0.x); a0.y = fmaf(w, v.y, a0.y);
        a0.z = fmaf(w, v.z, a0.z); a0.w = fmaf(w, v.w, a0.w);
    }
    float4 acc;
    acc.x = (a0.x + a1.x) + (a2.x + a3.x);
    acc.y = (a0.y + a1.y) + (a2.y + a3.y);
    acc.z = (a0.z + a1.z) + (a2.z + a3.z);
    acc.w = (a0.w + a1.w) + (a2.w + a3.w);
    if (scale2) {
        float4 p = prev[idx];
        acc.x = fmaf(2.f, acc.x, -p.x); acc.y = fmaf(2.f, acc.y, -p.y);
        acc.z = fmaf(2.f, acc.z, -p.z); acc.w = fmaf(2.f, acc.w, -p.w);
    }
    out[idx] = acc;
}

__global__ void prop_kernel(const float* __restrict__ feat, const float* prev,
                            float* out,
                            const int* __restrict__ row_ptr, const int* __restrict__ col,
                            const float* __restrict__ wv, int n, int dim, int scale2) {
    int idx = blockIdx.x * blockDim.x + threadIdx.x;
    if (idx >= n * dim) return;
    int nn = idx / dim;
    int f = idx - nn * dim;
    int e0 = row_ptr[nn], e1 = row_ptr[nn + 1];
    float a0 = 0.f, a1 = 0.f, a2 = 0.f, a3 = 0.f;
    int e = e0;
    for (; e + 4 <= e1; e += 4) {
        int c0 = col[e], c1 = col[e + 1], c2 = col[e + 2], c3 = col[e + 3];
        float w0 = wv[e], w1 = wv[e + 1], w2 = wv[e + 2], w3 = wv[e + 3];
        float v0 = feat[(size_t)c0 * dim + f];
        float v1 = feat[(size_t)c1 * dim + f];
        float v2 = feat[(size_t)c2 * dim + f];
        float v3 = feat[(size_t)c3 * dim + f];
        a0 = fmaf(w0, v0, a0); a1 = fmaf(w1, v1, a1);
        a2 = fmaf(w2, v2, a2); a3 = fmaf(w3, v3, a3);
    }
    for (; e < e1; ++e)
        a0 = fmaf(wv[e], feat[(size_t)col[e] * dim + f], a0);
    float acc = (a0 + a1) + (a2 + a3);
    out[idx] = scale2 ? fmaf(2.f, acc, -prev[idx]) : acc;
}

// ---------------- register-tiled GEMM, dout == 64, din % 4 == 0 ----------------
// 256 threads/block: 16 o-threads (4 outs each) x 16 n-rows (4 nodes each)
// => 64 nodes x 64 outs per block, 4x4 float accumulator tile per thread.
__global__ void gemm64_kernel(const float4* __restrict__ X4, const float4* __restrict__ W4,
                              const float4* __restrict__ bias4, float4* __restrict__ out4,
                              int n, int din4, int first, int bnrelu,
                              const float4* __restrict__ bn_g4, const float4* __restrict__ bn_b4,
                              const float4* __restrict__ bn_m4, const float4* __restrict__ bn_v4) {
    int t = threadIdx.x;
    int ot = t & 15;          // o-group: outs [ot*4, ot*4+4)
    int nr = t >> 4;          // n-row
    int nb = blockIdx.x * 64 + nr * 4;
    int ni[4];
#pragma unroll
    for (int i = 0; i < 4; ++i) ni[i] = min(nb + i, n - 1);

    float4 acc[4];
    if (first) {
        float4 bv = bias4[ot];
#pragma unroll
        for (int i = 0; i < 4; ++i) acc[i] = bv;
    } else {
#pragma unroll
        for (int i = 0; i < 4; ++i) acc[i] = out4[(size_t)ni[i] * 16 + ot];
    }

    for (int d4 = 0; d4 < din4; ++d4) {
        float4 xa[4];
#pragma unroll
        for (int i = 0; i < 4; ++i) xa[i] = X4[(size_t)ni[i] * din4 + d4];
        float4 wb[4];
#pragma unroll
        for (int j = 0; j < 4; ++j) wb[j] = W4[(size_t)(d4 * 4 + j) * 16 + ot];
#pragma unroll
        for (int i = 0; i < 4; ++i) {
            const float xs[4] = {xa[i].x, xa[i].y, xa[i].z, xa[i].w};
#pragma unroll
            for (int j = 0; j < 4; ++j) {
                acc[i].x = fmaf(xs[j], wb[j].x, acc[i].x);
                acc[i].y = fmaf(xs[j], wb[j].y, acc[i].y);
                acc[i].z = fmaf(xs[j], wb[j].z, acc[i].z);
                acc[i].w = fmaf(xs[j], wb[j].w, acc[i].w);
            }
        }
    }

    if (bnrelu) {
        float4 g = bn_g4[ot], b = bn_b4[ot], m = bn_m4[ot], v = bn_v4[ot];
        float4 sc;
        sc.x = g.x * rsqrtf(v.x + BN_EPS); sc.y = g.y * rsqrtf(v.y + BN_EPS);
        sc.z = g.z * rsqrtf(v.z + BN_EPS); sc.w = g.w * rsqrtf(v.w + BN_EPS);
#pragma unroll
        for (int i = 0; i < 4; ++i) {
            acc[i].x = fmaxf(fmaf(acc[i].x - m.x, sc.x, b.x), 0.f);
            acc[i].y = fmaxf(fmaf(acc[i].y - m.y, sc.y, b.y), 0.f);
            acc[i].z = fmaxf(fmaf(acc[i].z - m.z, sc.z, b.z), 0.f);
            acc[i].w = fmaxf(fmaf(acc[i].w - m.w, sc.w, b.w), 0.f);
        }
    }
#pragma unroll
    for (int i = 0; i < 4; ++i)
        if (nb + i < n) out4[(size_t)(nb + i) * 16 + ot] = acc[i];
}

// ---------------- small-dout GEMM: thread computes 4 nodes x DOUT outs ----------------
template <int DOUT>
__global__ void gemm_small_kernel(const float* __restrict__ X, const float* __restrict__ W,
                                  const float* __restrict__ bias, float* __restrict__ out,
                                  int n, int din, int first, int bnrelu,
                                  const float* __restrict__ bn_g, const float* __restrict__ bn_b,
                                  const float* __restrict__ bn_m, const float* __restrict__ bn_v) {
    int t = blockIdx.x * blockDim.x + threadIdx.x;
    int nb = t * 4;
    if (nb >= n) return;
    int ni[4];
#pragma unroll
    for (int i = 0; i < 4; ++i) ni[i] = min(nb + i, n - 1);

    float acc[4][DOUT];
    if (first) {
#pragma unroll
        for (int o = 0; o < DOUT; ++o) {
            float bv = bias[o];
#pragma unroll
            for (int i = 0; i < 4; ++i) acc[i][o] = bv;
        }
    } else {
#pragma unroll
        for (int i = 0; i < 4; ++i)
#pragma unroll
            for (int o = 0; o < DOUT; ++o) acc[i][o] = out[(size_t)ni[i] * DOUT + o];
    }

    int d = 0;
    if ((din & 3) == 0) {
        int din4 = din >> 2;
        const float4* X4 = reinterpret_cast<const float4*>(X);
        for (int d4 = 0; d4 < din4; ++d4) {
            float xs[4][4];
#pragma unroll
            for (int i = 0; i < 4; ++i) {
                float4 xv = X4[(size_t)ni[i] * din4 + d4];
                xs[i][0] = xv.x; xs[i][1] = xv.y; xs[i][2] = xv.z; xs[i][3] = xv.w;
            }
#pragma unroll
            for (int j = 0; j < 4; ++j) {
                int dd = d4 * 4 + j;
#pragma unroll
                for (int o = 0; o < DOUT; ++o) {
                    float w = W[(size_t)dd * DOUT + o];
                    acc[0][o] = fmaf(xs[0][j], w, acc[0][o]);
                    acc[1][o] = fmaf(xs[1][j], w, acc[1][o]);
                    acc[2][o] = fmaf(xs[2][j], w, acc[2][o]);
                    acc[3][o] = fmaf(xs[3][j], w, acc[3][o]);
                }
            }
        }
        d = din;
    }
    for (; d < din; ++d) {
        float xs0 = X[(size_t)ni[0] * din + d];
        float xs1 = X[(size_t)ni[1] * din + d];
        float xs2 = X[(size_t)ni[2] * din + d];
        float xs3 = X[(size_t)ni[3] * din + d];
#pragma unroll
        for (int o = 0; o < DOUT; ++o) {
            float w = W[(size_t)d * DOUT + o];
            acc[0][o] = fmaf(xs0, w, acc[0][o]);
            acc[1][o] = fmaf(xs1, w, acc[1][o]);
            acc[2][o] = fmaf(xs2, w, acc[2][o]);
            acc[3][o] = fmaf(xs3, w, acc[3][o]);
        }
    }

    if (bnrelu) {
#pragma unroll
        for (int o = 0; o < DOUT; ++o) {
            float sc = bn_g[o] * rsqrtf(bn_v[o] + BN_EPS);
            float mm = bn_m[o], bb = bn_b[o];
#pragma unroll
            for (int i = 0; i < 4; ++i)
                acc[i][o] = fmaxf(fmaf(acc[i][o] - mm, sc, bb), 0.f);
        }
    }
#pragma unroll
    for (int i = 0; i < 4; ++i)
        if (nb + i < n)
#pragma unroll
            for (int o = 0; o < DOUT; ++o) out[(size_t)(nb + i) * DOUT + o] = acc[i][o];
}

// ---------------- host driver ----------------

extern "C" void kernel_launch(void* const* d_in, const int* in_sizes, int n_in,
                              void* d_out, int out_size, void* d_ws, size_t ws_size,
                              hipStream_t stream) {
    const float* x  = (const float*)d_in[0];
    const int*   ei = (const int*)d_in[1];
    const float* Wl[4] = {(const float*)d_in[2], (const float*)d_in[4],
                          (const float*)d_in[6], (const float*)d_in[8]};
    const float* bl[4] = {(const float*)d_in[3], (const float*)d_in[5],
                          (const float*)d_in[7], (const float*)d_in[9]};
    const float* bn[3][4];
    for (int l = 0; l < 3; ++l)
        for (int j = 0; j < 4; ++j)
            bn[l][j] = (const float*)d_in[10 + 4 * l + j];

    char* ws = (char*)d_ws;
    auto alloc = [&](size_t bytes) -> void* {
        void* p = (void*)ws;
        ws += (bytes + 255) & ~(size_t)255;
        return p;
    };
    int*   deg     = (int*)alloc(NN * 4);
    int*   row_ptr = (int*)alloc((NN + 1) * 4);
    int*   cursor  = (int*)alloc(NN * 4);
    float* dinv    = (float*)alloc(NN * 4);
    int*   col     = (int*)alloc(NE * 4);
    float* wv      = (float*)alloc(NE * 4);
    float* P       = (float*)alloc((size_t)NN * 128 * 4);
    float* Q       = (float*)alloc((size_t)NN * 128 * 4);
    float* H1      = (float*)alloc((size_t)NN * 64 * 4);
    float* H2      = (float*)alloc((size_t)NN * 18 * 4);
    float* H3      = (float*)alloc((size_t)NN * 9 * 4);

    const int* srcp = ei;
    const int* dstp = ei + NE;

    hipMemsetAsync(deg, 0, NN * 4, stream);
    hipMemsetAsync(cursor, 0, NN * 4, stream);
    hist_kernel<<<divup(NE, 256), 256, 0, stream>>>(dstp, deg, NE);
    scan_kernel<<<1, 1024, 0, stream>>>(deg, row_ptr, NN);
    dinv_kernel<<<divup(NN, 256), 256, 0, stream>>>(deg, dinv, NN);
    scatter_kernel<<<divup(NE, 256), 256, 0, stream>>>(srcp, dstp, row_ptr, cursor, dinv,
                                                       col, wv, NE);

    auto prop = [&](const float* feat, const float* prev, float* out, int dim, int scale2) {
        if ((dim & 3) == 0) {
            int dim4 = dim >> 2;
            int pt = NN * dim4;
            prop4_kernel<<<divup(pt, 256), 256, 0, stream>>>(
                (const float4*)feat, (const float4*)prev, (float4*)out,
                row_ptr, col, wv, NN, dim4, scale2);
        } else {
            int pt = NN * dim;
            prop_kernel<<<divup(pt, 256), 256, 0, stream>>>(
                feat, prev, out, row_ptr, col, wv, NN, dim, scale2);
        }
    };

    auto gemm = [&](const float* X, int din, int dout, const float* W, const float* b,
                    float* outl, int first, int bnrelu,
                    const float* g, const float* bb, const float* m, const float* v) {
        if (dout == 64 && (din & 3) == 0) {
            gemm64_kernel<<<divup(NN, 64), 256, 0, stream>>>(
                (const float4*)X, (const float4*)W, (const float4*)b, (float4*)outl,
                NN, din >> 2, first, bnrelu,
                (const float4*)g, (const float4*)bb, (const float4*)m, (const float4*)v);
        } else if (dout == 18) {
            gemm_small_kernel<18><<<divup(NN, 1024), 256, 0, stream>>>(
                X, W, b, outl, NN, din, first, bnrelu, g, bb, m, v);
        } else if (dout == 9) {
            gemm_small_kernel<9><<<divup(NN, 1024), 256, 0, stream>>>(
                X, W, b, outl, NN, din, first, bnrelu, g, bb, m, v);
        } else { // dout == 10
            gemm_small_kernel<10><<<divup(NN, 1024), 256, 0, stream>>>(
                X, W, b, outl, NN, din, first, bnrelu, g, bb, m, v);
        }
    };

    auto run_layer = [&](const float* xin, int din, int dout, int K,
                         const float* W, const float* b, float* outl,
                         const float* g, const float* bb, const float* m, const float* v) {
        int last = K - 1;
        gemm(xin, din, dout, W, b, outl, 1, (last == 0 && g) ? 1 : 0, g, bb, m, v);
        if (K < 2) return;
        prop(xin, nullptr, Q, din, 0);
        gemm(Q, din, dout, W + (size_t)din * dout, nullptr, outl, 0,
             (last == 1 && g) ? 1 : 0, g, bb, m, v);
        const float* t0 = xin;
        float* t1 = Q;
        for (int k = 2; k < K; ++k) {
            float* t2 = (t0 == xin) ? P : (float*)t0;
            prop(t1, t0, t2, din, 1);
            gemm(t2, din, dout, W + (size_t)k * din * dout, nullptr, outl, 0,
                 (last == k && g) ? 1 : 0, g, bb, m, v);
            t0 = t1;
            t1 = t2;
        }
    };

    run_layer(x,  128, 64, 8, Wl[0], bl[0], H1, bn[0][0], bn[0][1], bn[0][2], bn[0][3]);
    run_layer(H1,  64, 18, 6, Wl[1], bl[1], H2, bn[1][0], bn[1][1], bn[1][2], bn[1][3]);
    run_layer(H2,  18,  9, 4, Wl[2], bl[2], H3, bn[2][0], bn[2][1], bn[2][2], bn[2][3]);
    run_layer(H3,   9, 10, 4, Wl[3], bl[3], (float*)d_out, nullptr, nullptr, nullptr, nullptr);
}

// Round 4
// 1755.166 us; speedup vs baseline: 3.0078x; 1.3872x over previous
//
#include <hip/hip_runtime.h>

#define NN 100000
#define NE 1600000
#define BN_EPS 1e-5f

static inline int divup(int a, int b) { return (a + b - 1) / b; }

// ---------------- preprocessing ----------------

__global__ void hist_kernel(const int* __restrict__ dst, int* __restrict__ deg, int e) {
    int i = blockIdx.x * blockDim.x + threadIdx.x;
    if (i < e) atomicAdd(&deg[dst[i]], 1);
}

// 3-stage parallel exclusive scan: 1024 elems/block, 4/thread
__global__ void blksum_kernel(const int* __restrict__ deg, int* __restrict__ blk, int n) {
    __shared__ int red[256];
    int t = threadIdx.x;
    int base = blockIdx.x * 1024 + t * 4;
    int s = 0;
#pragma unroll
    for (int i = 0; i < 4; ++i) {
        int idx = base + i;
        if (idx < n) s += deg[idx];
    }
    red[t] = s;
    __syncthreads();
    for (int off = 128; off > 0; off >>= 1) {
        if (t < off) red[t] += red[t + off];
        __syncthreads();
    }
    if (t == 0) blk[blockIdx.x] = red[0];
}

__global__ void blkscan_kernel(int* __restrict__ blk, int nb, int* __restrict__ row_ptr, int n) {
    __shared__ int sh[256];
    int t = threadIdx.x;
    int v = (t < nb) ? blk[t] : 0;
    sh[t] = v;
    __syncthreads();
    for (int off = 1; off < 256; off <<= 1) {
        int u = (t >= off) ? sh[t - off] : 0;
        __syncthreads();
        sh[t] += u;
        __syncthreads();
    }
    if (t < nb) blk[t] = (t == 0) ? 0 : sh[t - 1];
    if (t == nb - 1) row_ptr[n] = sh[t];  // grand total
}

__global__ void emit_kernel(const int* __restrict__ deg, const int* __restrict__ blk,
                            int* __restrict__ row_ptr, int n) {
    __shared__ int red[256];
    int t = threadIdx.x;
    int base = blockIdx.x * 1024 + t * 4;
    int d[4];
    int s = 0;
#pragma unroll
    for (int i = 0; i < 4; ++i) {
        int idx = base + i;
        d[i] = (idx < n) ? deg[idx] : 0;
        s += d[i];
    }
    red[t] = s;
    __syncthreads();
    for (int off = 1; off < 256; off <<= 1) {
        int u = (t >= off) ? red[t - off] : 0;
        __syncthreads();
        red[t] += u;
        __syncthreads();
    }
    int run = blk[blockIdx.x] + ((t == 0) ? 0 : red[t - 1]);
#pragma unroll
    for (int i = 0; i < 4; ++i) {
        int idx = base + i;
        if (idx < n) { row_ptr[idx] = run; run += d[i]; }
    }
}

__global__ void dinv_kernel(const int* __restrict__ deg, float* __restrict__ dinv, int n) {
    int i = blockIdx.x * blockDim.x + threadIdx.x;
    if (i < n) {
        int d = deg[i];
        dinv[i] = (d > 0) ? rsqrtf((float)d) : 0.f;
    }
}

__global__ void scatter_kernel(const int* __restrict__ src, const int* __restrict__ dst,
                               const int* __restrict__ row_ptr, int* __restrict__ cursor,
                               const float* __restrict__ dinv,
                               int* __restrict__ col, float* __restrict__ wv, int e) {
    int i = blockIdx.x * blockDim.x + threadIdx.x;
    if (i >= e) return;
    int s = src[i], d = dst[i];
    int pos = row_ptr[d] + atomicAdd(&cursor[d], 1);
    col[pos] = s;
    wv[pos] = -dinv[s] * dinv[d];
}

// ---------------- Clenshaw propagation ----------------
// out = scale * (L_hat @ feat) - (has_sub ? sub : 0)
// float4 variant (dim % 4 == 0)
__global__ void prop4c_kernel(const float4* __restrict__ feat, const float4* __restrict__ sub,
                              float4* __restrict__ out,
                              const int* __restrict__ row_ptr, const int* __restrict__ col,
                              const float* __restrict__ wv, int n, int dim4,
                              float scale, int has_sub) {
    int idx = blockIdx.x * blockDim.x + threadIdx.x;
    if (idx >= n * dim4) return;
    int nn = idx / dim4;
    int f = idx - nn * dim4;
    int e0 = row_ptr[nn], e1 = row_ptr[nn + 1];
    float4 a0 = {0.f, 0.f, 0.f, 0.f}, a1 = a0, a2 = a0, a3 = a0;
    int e = e0;
    for (; e + 4 <= e1; e += 4) {
        int c0 = col[e], c1 = col[e + 1], c2 = col[e + 2], c3 = col[e + 3];
        float w0 = wv[e], w1 = wv[e + 1], w2 = wv[e + 2], w3 = wv[e + 3];
        float4 v0 = feat[(size_t)c0 * dim4 + f];
        float4 v1 = feat[(size_t)c1 * dim4 + f];
        float4 v2 = feat[(size_t)c2 * dim4 + f];
        float4 v3 = feat[(size_t)c3 * dim4 + f];
        a0.x = fmaf(w0, v0.x, a0.x); a0.y = fmaf(w0, v0.y, a0.y);
        a0.z = fmaf(w0, v0.z, a0.z); a0.w = fmaf(w0, v0.w, a0.w);
        a1.x = fmaf(w1, v1.x, a1.x); a1.y = fmaf(w1, v1.y, a1.y);
        a1.z = fmaf(w1, v1.z, a1.z); a1.w = fmaf(w1, v1.w, a1.w);
        a2.x = fmaf(w2, v2.x, a2.x); a2.y = fmaf(w2, v2.y, a2.y);
        a2.z = fmaf(w2, v2.z, a2.z); a2.w = fmaf(w2, v2.w, a2.w);
        a3.x = fmaf(w3, v3.x, a3.x); a3.y = fmaf(w3, v3.y, a3.y);
        a3.z = fmaf(w3, v3.z, a3.z); a3.w = fmaf(w3, v3.w, a3.w);
    }
    for (; e < e1; ++e) {
        int c = col[e]; float w = wv[e];
        float4 v = feat[(size_t)c * dim4 + f];
        a0.x = fmaf(w, v.x, a0.x); a0.y = fmaf(w, v.y, a0.y);
        a0.z = fmaf(w, v.z, a0.z); a0.w = fmaf(w, v.w, a0.w);
    }
    float4 acc;
    acc.x = (a0.x + a1.x) + (a2.x + a3.x);
    acc.y = (a0.y + a1.y) + (a2.y + a3.y);
    acc.z = (a0.z + a1.z) + (a2.z + a3.z);
    acc.w = (a0.w + a1.w) + (a2.w + a3.w);
    if (has_sub) {
        float4 p = sub[idx];
        acc.x = fmaf(scale, acc.x, -p.x); acc.y = fmaf(scale, acc.y, -p.y);
        acc.z = fmaf(scale, acc.z, -p.z); acc.w = fmaf(scale, acc.w, -p.w);
    } else {
        acc.x *= scale; acc.y *= scale; acc.z *= scale; acc.w *= scale;
    }
    out[idx] = acc;
}

// scalar variant (any dim)
__global__ void propc_kernel(const float* __restrict__ feat, const float* __restrict__ sub,
                             float* __restrict__ out,
                             const int* __restrict__ row_ptr, const int* __restrict__ col,
                             const float* __restrict__ wv, int n, int dim,
                             float scale, int has_sub) {
    int idx = blockIdx.x * blockDim.x + threadIdx.x;
    if (idx >= n * dim) return;
    int nn = idx / dim;
    int f = idx - nn * dim;
    int e0 = row_ptr[nn], e1 = row_ptr[nn + 1];
    float a0 = 0.f, a1 = 0.f, a2 = 0.f, a3 = 0.f;
    int e = e0;
    for (; e + 4 <= e1; e += 4) {
        int c0 = col[e], c1 = col[e + 1], c2 = col[e + 2], c3 = col[e + 3];
        float w0 = wv[e], w1 = wv[e + 1], w2 = wv[e + 2], w3 = wv[e + 3];
        float v0 = feat[(size_t)c0 * dim + f];
        float v1 = feat[(size_t)c1 * dim + f];
        float v2 = feat[(size_t)c2 * dim + f];
        float v3 = feat[(size_t)c3 * dim + f];
        a0 = fmaf(w0, v0, a0); a1 = fmaf(w1, v1, a1);
        a2 = fmaf(w2, v2, a2); a3 = fmaf(w3, v3, a3);
    }
    for (; e < e1; ++e)
        a0 = fmaf(wv[e], feat[(size_t)col[e] * dim + f], a0);
    float acc = (a0 + a1) + (a2 + a3);
    acc = has_sub ? fmaf(scale, acc, -sub[idx]) : acc * scale;
    out[idx] = acc;
}

// ---------------- register-tiled GEMM, dout == 64, din % 4 == 0 ----------------
// acc = (first ? 0 : out) + (bias ? bias : 0) + X@W ; optional fused BN+ReLU
__global__ void gemm64_kernel(const float4* __restrict__ X4, const float4* __restrict__ W4,
                              const float4* __restrict__ bias4, float4* __restrict__ out4,
                              int n, int din4, int first, int bnrelu,
                              const float4* __restrict__ bn_g4, const float4* __restrict__ bn_b4,
                              const float4* __restrict__ bn_m4, const float4* __restrict__ bn_v4) {
    int t = threadIdx.x;
    int ot = t & 15;
    int nr = t >> 4;
    int nb = blockIdx.x * 64 + nr * 4;
    int ni[4];
#pragma unroll
    for (int i = 0; i < 4; ++i) ni[i] = min(nb + i, n - 1);

    float4 bv = {0.f, 0.f, 0.f, 0.f};
    if (bias4) bv = bias4[ot];
    float4 acc[4];
#pragma unroll
    for (int i = 0; i < 4; ++i) {
        if (first) acc[i] = bv;
        else {
            acc[i] = out4[(size_t)ni[i] * 16 + ot];
            acc[i].x += bv.x; acc[i].y += bv.y; acc[i].z += bv.z; acc[i].w += bv.w;
        }
    }

    for (int d4 = 0; d4 < din4; ++d4) {
        float4 xa[4];
#pragma unroll
        for (int i = 0; i < 4; ++i) xa[i] = X4[(size_t)ni[i] * din4 + d4];
        float4 wb[4];
#pragma unroll
        for (int j = 0; j < 4; ++j) wb[j] = W4[(size_t)(d4 * 4 + j) * 16 + ot];
#pragma unroll
        for (int i = 0; i < 4; ++i) {
            const float xs[4] = {xa[i].x, xa[i].y, xa[i].z, xa[i].w};
#pragma unroll
            for (int j = 0; j < 4; ++j) {
                acc[i].x = fmaf(xs[j], wb[j].x, acc[i].x);
                acc[i].y = fmaf(xs[j], wb[j].y, acc[i].y);
                acc[i].z = fmaf(xs[j], wb[j].z, acc[i].z);
                acc[i].w = fmaf(xs[j], wb[j].w, acc[i].w);
            }
        }
    }

    if (bnrelu) {
        float4 g = bn_g4[ot], b = bn_b4[ot], m = bn_m4[ot], v = bn_v4[ot];
        float4 sc;
        sc.x = g.x * rsqrtf(v.x + BN_EPS); sc.y = g.y * rsqrtf(v.y + BN_EPS);
        sc.z = g.z * rsqrtf(v.z + BN_EPS); sc.w = g.w * rsqrtf(v.w + BN_EPS);
#pragma unroll
        for (int i = 0; i < 4; ++i) {
            acc[i].x = fmaxf(fmaf(acc[i].x - m.x, sc.x, b.x), 0.f);
            acc[i].y = fmaxf(fmaf(acc[i].y - m.y, sc.y, b.y), 0.f);
            acc[i].z = fmaxf(fmaf(acc[i].z - m.z, sc.z, b.z), 0.f);
            acc[i].w = fmaxf(fmaf(acc[i].w - m.w, sc.w, b.w), 0.f);
        }
    }
#pragma unroll
    for (int i = 0; i < 4; ++i)
        if (nb + i < n) out4[(size_t)(nb + i) * 16 + ot] = acc[i];
}

// ---------------- small-dout GEMM: thread computes 4 nodes x DOUT outs ----------------
template <int DOUT>
__global__ void gemm_small_kernel(const float* __restrict__ X, const float* __restrict__ W,
                                  const float* __restrict__ bias, float* __restrict__ out,
                                  int n, int din, int first, int bnrelu,
                                  const float* __restrict__ bn_g, const float* __restrict__ bn_b,
                                  const float* __restrict__ bn_m, const float* __restrict__ bn_v) {
    int t = blockIdx.x * blockDim.x + threadIdx.x;
    int nb = t * 4;
    if (nb >= n) return;
    int ni[4];
#pragma unroll
    for (int i = 0; i < 4; ++i) ni[i] = min(nb + i, n - 1);

    float acc[4][DOUT];
#pragma unroll
    for (int o = 0; o < DOUT; ++o) {
        float bv = bias ? bias[o] : 0.f;
#pragma unroll
        for (int i = 0; i < 4; ++i)
            acc[i][o] = (first ? 0.f : out[(size_t)ni[i] * DOUT + o]) + bv;
    }

    int d = 0;
    if ((din & 3) == 0) {
        int din4 = din >> 2;
        const float4* X4 = reinterpret_cast<const float4*>(X);
        for (int d4 = 0; d4 < din4; ++d4) {
            float xs[4][4];
#pragma unroll
            for (int i = 0; i < 4; ++i) {
                float4 xv = X4[(size_t)ni[i] * din4 + d4];
                xs[i][0] = xv.x; xs[i][1] = xv.y; xs[i][2] = xv.z; xs[i][3] = xv.w;
            }
#pragma unroll
            for (int j = 0; j < 4; ++j) {
                int dd = d4 * 4 + j;
#pragma unroll
                for (int o = 0; o < DOUT; ++o) {
                    float w = W[(size_t)dd * DOUT + o];
                    acc[0][o] = fmaf(xs[0][j], w, acc[0][o]);
                    acc[1][o] = fmaf(xs[1][j], w, acc[1][o]);
                    acc[2][o] = fmaf(xs[2][j], w, acc[2][o]);
                    acc[3][o] = fmaf(xs[3][j], w, acc[3][o]);
                }
            }
        }
        d = din;
    }
    for (; d < din; ++d) {
        float xs0 = X[(size_t)ni[0] * din + d];
        float xs1 = X[(size_t)ni[1] * din + d];
        float xs2 = X[(size_t)ni[2] * din + d];
        float xs3 = X[(size_t)ni[3] * din + d];
#pragma unroll
        for (int o = 0; o < DOUT; ++o) {
            float w = W[(size_t)d * DOUT + o];
            acc[0][o] = fmaf(xs0, w, acc[0][o]);
            acc[1][o] = fmaf(xs1, w, acc[1][o]);
            acc[2][o] = fmaf(xs2, w, acc[2][o]);
            acc[3][o] = fmaf(xs3, w, acc[3][o]);
        }
    }

    if (bnrelu) {
#pragma unroll
        for (int o = 0; o < DOUT; ++o) {
            float sc = bn_g[o] * rsqrtf(bn_v[o] + BN_EPS);
            float mm = bn_m[o], bb = bn_b[o];
#pragma unroll
            for (int i = 0; i < 4; ++i)
                acc[i][o] = fmaxf(fmaf(acc[i][o] - mm, sc, bb), 0.f);
        }
    }
#pragma unroll
    for (int i = 0; i < 4; ++i)
        if (nb + i < n)
#pragma unroll
            for (int o = 0; o < DOUT; ++o) out[(size_t)(nb + i) * DOUT + o] = acc[i][o];
}

// ---------------- host driver ----------------

extern "C" void kernel_launch(void* const* d_in, const int* in_sizes, int n_in,
                              void* d_out, int out_size, void* d_ws, size_t ws_size,
                              hipStream_t stream) {
    const float* x  = (const float*)d_in[0];
    const int*   ei = (const int*)d_in[1];
    const float* Wl[4] = {(const float*)d_in[2], (const float*)d_in[4],
                          (const float*)d_in[6], (const float*)d_in[8]};
    const float* bl[4] = {(const float*)d_in[3], (const float*)d_in[5],
                          (const float*)d_in[7], (const float*)d_in[9]};
    const float* bn[3][4];
    for (int l = 0; l < 3; ++l)
        for (int j = 0; j < 4; ++j)
            bn[l][j] = (const float*)d_in[10 + 4 * l + j];

    char* ws = (char*)d_ws;
    auto alloc = [&](size_t bytes) -> void* {
        void* p = (void*)ws;
        ws += (bytes + 255) & ~(size_t)255;
        return p;
    };
    int*   deg     = (int*)alloc(NN * 4);
    int*   row_ptr = (int*)alloc((NN + 1) * 4);
    int*   cursor  = (int*)alloc(NN * 4);
    int*   blks    = (int*)alloc(128 * 4);
    float* dinv    = (float*)alloc(NN * 4);
    int*   col     = (int*)alloc(NE * 4);
    float* wv      = (float*)alloc(NE * 4);
    float* B1      = (float*)alloc((size_t)NN * 64 * 4);
    float* B2      = (float*)alloc((size_t)NN * 64 * 4);
    float* B3      = (float*)alloc((size_t)NN * 64 * 4);
    float* H1      = (float*)alloc((size_t)NN * 64 * 4);
    float* H2      = (float*)alloc((size_t)NN * 18 * 4);
    float* H3      = (float*)alloc((size_t)NN * 9 * 4);

    const int* srcp = ei;
    const int* dstp = ei + NE;
    const int nscan = divup(NN, 1024);  // 98 blocks <= 256

    hipMemsetAsync(deg, 0, NN * 4, stream);
    hipMemsetAsync(cursor, 0, NN * 4, stream);
    hist_kernel<<<divup(NE, 256), 256, 0, stream>>>(dstp, deg, NE);
    blksum_kernel<<<nscan, 256, 0, stream>>>(deg, blks, NN);
    blkscan_kernel<<<1, 256, 0, stream>>>(blks, nscan, row_ptr, NN);
    emit_kernel<<<nscan, 256, 0, stream>>>(deg, blks, row_ptr, NN);
    dinv_kernel<<<divup(NN, 256), 256, 0, stream>>>(deg, dinv, NN);
    scatter_kernel<<<divup(NE, 256), 256, 0, stream>>>(srcp, dstp, row_ptr, cursor, dinv,
                                                       col, wv, NE);

    auto prop = [&](const float* feat, const float* sub, float* out, int dim,
                    float scale, int has_sub) {
        if ((dim & 3) == 0) {
            int dim4 = dim >> 2;
            prop4c_kernel<<<divup(NN * dim4, 256), 256, 0, stream>>>(
                (const float4*)feat, (const float4*)sub, (float4*)out,
                row_ptr, col, wv, NN, dim4, scale, has_sub);
        } else {
            propc_kernel<<<divup(NN * dim, 256), 256, 0, stream>>>(
                feat, sub, out, row_ptr, col, wv, NN, dim, scale, has_sub);
        }
    };

    auto gemm = [&](const float* X, int din, int dout, const float* W, const float* b,
                    float* outl, int first, int bnrelu,
                    const float* g, const float* bb, const float* m, const float* v) {
        if (dout == 64 && (din & 3) == 0) {
            gemm64_kernel<<<divup(NN, 64), 256, 0, stream>>>(
                (const float4*)X, (const float4*)W, (const float4*)b, (float4*)outl,
                NN, din >> 2, first, bnrelu,
                (const float4*)g, (const float4*)bb, (const float4*)m, (const float4*)v);
        } else if (dout == 18) {
            gemm_small_kernel<18><<<divup(NN, 1024), 256, 0, stream>>>(
                X, W, b, outl, NN, din, first, bnrelu, g, bb, m, v);
        } else if (dout == 9) {
            gemm_small_kernel<9><<<divup(NN, 1024), 256, 0, stream>>>(
                X, W, b, outl, NN, din, first, bnrelu, g, bb, m, v);
        } else { // dout == 10
            gemm_small_kernel<10><<<divup(NN, 1024), 256, 0, stream>>>(
                X, W, b, outl, NN, din, first, bnrelu, g, bb, m, v);
        }
    };

    // Clenshaw: b_k = 2 L b_{k+1} - b_{k+2} + X W_k ; out = L b_1 - b_2 + X W_0 (+bias, BN, ReLU)
    auto run_layer = [&](const float* xin, int din, int dout, int K,
                         const float* W, const float* b, float* outl,
                         const float* g, const float* bb, const float* m, const float* v) {
        // b_{K-1} = X @ W_{K-1}
        gemm(xin, din, dout, W + (size_t)(K - 1) * din * dout, nullptr, B1, 1, 0,
             nullptr, nullptr, nullptr, nullptr);
        const float* b1 = B1;
        const float* b2 = nullptr;
        float* freeb = B2;
        float* other = B3;
        for (int k = K - 2; k >= 1; --k) {
            float* tmp = freeb;
            prop(b1, b2, tmp, dout, 2.f, b2 != nullptr);
            gemm(xin, din, dout, W + (size_t)k * din * dout, nullptr, tmp, 0, 0,
                 nullptr, nullptr, nullptr, nullptr);
            freeb = b2 ? (float*)b2 : other;
            b2 = b1;
            b1 = tmp;
        }
        // final: out = L b_1 - b_2 + X W_0 + bias, then BN+ReLU if requested
        prop(b1, b2, outl, dout, 1.f, b2 != nullptr);
        gemm(xin, din, dout, W, b, outl, 0, g ? 1 : 0, g, bb, m, v);
    };

    run_layer(x,  128, 64, 8, Wl[0], bl[0], H1, bn[0][0], bn[0][1], bn[0][2], bn[0][3]);
    run_layer(H1,  64, 18, 6, Wl[1], bl[1], H2, bn[1][0], bn[1][1], bn[1][2], bn[1][3]);
    run_layer(H2,  18,  9, 4, Wl[2], bl[2], H3, bn[2][0], bn[2][1], bn[2][2], bn[2][3]);
    run_layer(H3,   9, 10, 4, Wl[3], bl[3], (float*)d_out, nullptr, nullptr, nullptr, nullptr);
}

// Round 5
// 1694.627 us; speedup vs baseline: 3.1152x; 1.0357x over previous
//
#include <hip/hip_runtime.h>

#define NN 100000
#define NE 1600000
#define BN_EPS 1e-5f

static inline int divup(int a, int b) { return (a + b - 1) / b; }

// ---------------- preprocessing ----------------

__global__ void hist_kernel(const int* __restrict__ dst, int* __restrict__ deg, int e) {
    int i = blockIdx.x * blockDim.x + threadIdx.x;
    if (i < e) atomicAdd(&deg[dst[i]], 1);
}

__global__ void blksum_kernel(const int* __restrict__ deg, int* __restrict__ blk, int n) {
    __shared__ int red[256];
    int t = threadIdx.x;
    int base = blockIdx.x * 1024 + t * 4;
    int s = 0;
#pragma unroll
    for (int i = 0; i < 4; ++i) {
        int idx = base + i;
        if (idx < n) s += deg[idx];
    }
    red[t] = s;
    __syncthreads();
    for (int off = 128; off > 0; off >>= 1) {
        if (t < off) red[t] += red[t + off];
        __syncthreads();
    }
    if (t == 0) blk[blockIdx.x] = red[0];
}

__global__ void blkscan_kernel(int* __restrict__ blk, int nb, int* __restrict__ row_ptr, int n) {
    __shared__ int sh[256];
    int t = threadIdx.x;
    int v = (t < nb) ? blk[t] : 0;
    sh[t] = v;
    __syncthreads();
    for (int off = 1; off < 256; off <<= 1) {
        int u = (t >= off) ? sh[t - off] : 0;
        __syncthreads();
        sh[t] += u;
        __syncthreads();
    }
    if (t < nb) blk[t] = (t == 0) ? 0 : sh[t - 1];
    if (t == nb - 1) row_ptr[n] = sh[t];
}

__global__ void emit_kernel(const int* __restrict__ deg, const int* __restrict__ blk,
                            int* __restrict__ row_ptr, int n) {
    __shared__ int red[256];
    int t = threadIdx.x;
    int base = blockIdx.x * 1024 + t * 4;
    int d[4];
    int s = 0;
#pragma unroll
    for (int i = 0; i < 4; ++i) {
        int idx = base + i;
        d[i] = (idx < n) ? deg[idx] : 0;
        s += d[i];
    }
    red[t] = s;
    __syncthreads();
    for (int off = 1; off < 256; off <<= 1) {
        int u = (t >= off) ? red[t - off] : 0;
        __syncthreads();
        red[t] += u;
        __syncthreads();
    }
    int run = blk[blockIdx.x] + ((t == 0) ? 0 : red[t - 1]);
#pragma unroll
    for (int i = 0; i < 4; ++i) {
        int idx = base + i;
        if (idx < n) { row_ptr[idx] = run; run += d[i]; }
    }
}

__global__ void dinv_kernel(const int* __restrict__ deg, float* __restrict__ dinv, int n) {
    int i = blockIdx.x * blockDim.x + threadIdx.x;
    if (i < n) {
        int d = deg[i];
        dinv[i] = (d > 0) ? rsqrtf((float)d) : 0.f;
    }
}

// packed CSR payload: one 8B store per edge (halves scattered-write line traffic)
__global__ void scatter_kernel(const int* __restrict__ src, const int* __restrict__ dst,
                               const int* __restrict__ row_ptr, int* __restrict__ cursor,
                               const float* __restrict__ dinv,
                               int2* __restrict__ cw, int e) {
    int i = blockIdx.x * blockDim.x + threadIdx.x;
    if (i >= e) return;
    int s = src[i], d = dst[i];
    int pos = row_ptr[d] + atomicAdd(&cursor[d], 1);
    cw[pos] = make_int2(s, __float_as_int(-dinv[s] * dinv[d]));
}

// ---------------- fused Clenshaw propagation (float4 rows; dim4 == row stride) ----------
// out = scale*(L@feat) - (has_sub?sub:0) + (has_add?add:0), optional fused BN+ReLU.
__global__ void prop4f_kernel(const float4* __restrict__ feat, const float4* __restrict__ sub,
                              const float4* __restrict__ add, float4* __restrict__ out,
                              const int* __restrict__ row_ptr, const int2* __restrict__ cw,
                              int n, int dim4, float scale, int has_sub, int has_add,
                              int bnrelu, int used,
                              const float* __restrict__ bn_g, const float* __restrict__ bn_b,
                              const float* __restrict__ bn_m, const float* __restrict__ bn_v) {
    int idx = blockIdx.x * blockDim.x + threadIdx.x;
    if (idx >= n * dim4) return;
    int nd = idx / dim4;
    int f = idx - nd * dim4;
    int e0 = row_ptr[nd], e1 = row_ptr[nd + 1];
    float4 a0 = {0.f, 0.f, 0.f, 0.f}, a1 = a0, a2 = a0, a3 = a0;
    int e = e0;
    for (; e + 4 <= e1; e += 4) {
        int2 q0 = cw[e], q1 = cw[e + 1], q2 = cw[e + 2], q3 = cw[e + 3];
        float4 v0 = feat[(size_t)q0.x * dim4 + f];
        float4 v1 = feat[(size_t)q1.x * dim4 + f];
        float4 v2 = feat[(size_t)q2.x * dim4 + f];
        float4 v3 = feat[(size_t)q3.x * dim4 + f];
        float w0 = __int_as_float(q0.y), w1 = __int_as_float(q1.y);
        float w2 = __int_as_float(q2.y), w3 = __int_as_float(q3.y);
        a0.x = fmaf(w0, v0.x, a0.x); a0.y = fmaf(w0, v0.y, a0.y);
        a0.z = fmaf(w0, v0.z, a0.z); a0.w = fmaf(w0, v0.w, a0.w);
        a1.x = fmaf(w1, v1.x, a1.x); a1.y = fmaf(w1, v1.y, a1.y);
        a1.z = fmaf(w1, v1.z, a1.z); a1.w = fmaf(w1, v1.w, a1.w);
        a2.x = fmaf(w2, v2.x, a2.x); a2.y = fmaf(w2, v2.y, a2.y);
        a2.z = fmaf(w2, v2.z, a2.z); a2.w = fmaf(w2, v2.w, a2.w);
        a3.x = fmaf(w3, v3.x, a3.x); a3.y = fmaf(w3, v3.y, a3.y);
        a3.z = fmaf(w3, v3.z, a3.z); a3.w = fmaf(w3, v3.w, a3.w);
    }
    for (; e < e1; ++e) {
        int2 q = cw[e];
        float w = __int_as_float(q.y);
        float4 v = feat[(size_t)q.x * dim4 + f];
        a0.x = fmaf(w, v.x, a0.x); a0.y = fmaf(w, v.y, a0.y);
        a0.z = fmaf(w, v.z, a0.z); a0.w = fmaf(w, v.w, a0.w);
    }
    float r[4];
    r[0] = ((a0.x + a1.x) + (a2.x + a3.x)) * scale;
    r[1] = ((a0.y + a1.y) + (a2.y + a3.y)) * scale;
    r[2] = ((a0.z + a1.z) + (a2.z + a3.z)) * scale;
    r[3] = ((a0.w + a1.w) + (a2.w + a3.w)) * scale;
    if (has_sub) {
        float4 s4 = sub[idx];
        r[0] -= s4.x; r[1] -= s4.y; r[2] -= s4.z; r[3] -= s4.w;
    }
    if (has_add) {
        float4 c4 = add[idx];
        r[0] += c4.x; r[1] += c4.y; r[2] += c4.z; r[3] += c4.w;
    }
    if (bnrelu) {
#pragma unroll
        for (int c = 0; c < 4; ++c) {
            int o = f * 4 + c;
            if (o < used) {
                float sc = bn_g[o] * rsqrtf(bn_v[o] + BN_EPS);
                r[c] = fmaxf(fmaf(r[c] - bn_m[o], sc, bn_b[o]), 0.f);
            } else r[c] = 0.f;
        }
    }
    out[idx] = make_float4(r[0], r[1], r[2], r[3]);
}

// layer-4 final: feat/sub/add stride 12, out stride 10 (d_out), dims 10, scale 1
__global__ void propl_kernel(const float* __restrict__ feat, const float* __restrict__ sub,
                             const float* __restrict__ add, float* __restrict__ out,
                             const int* __restrict__ row_ptr, const int2* __restrict__ cw, int n) {
    int idx = blockIdx.x * blockDim.x + threadIdx.x;
    if (idx >= n * 10) return;
    int nd = idx / 10;
    int o = idx - nd * 10;
    int e0 = row_ptr[nd], e1 = row_ptr[nd + 1];
    float a0 = 0.f, a1 = 0.f, a2 = 0.f, a3 = 0.f;
    int e = e0;
    for (; e + 4 <= e1; e += 4) {
        int2 q0 = cw[e], q1 = cw[e + 1], q2 = cw[e + 2], q3 = cw[e + 3];
        a0 = fmaf(__int_as_float(q0.y), feat[(size_t)q0.x * 12 + o], a0);
        a1 = fmaf(__int_as_float(q1.y), feat[(size_t)q1.x * 12 + o], a1);
        a2 = fmaf(__int_as_float(q2.y), feat[(size_t)q2.x * 12 + o], a2);
        a3 = fmaf(__int_as_float(q3.y), feat[(size_t)q3.x * 12 + o], a3);
    }
    for (; e < e1; ++e) {
        int2 q = cw[e];
        a0 = fmaf(__int_as_float(q.y), feat[(size_t)q.x * 12 + o], a0);
    }
    float acc = (a0 + a1) + (a2 + a3);
    out[idx] = acc - sub[(size_t)nd * 12 + o] + add[(size_t)nd * 12 + o];
}

// ---------------- batched GEMM into K slices (layer 1, dout=64) ----------------
__global__ void gemm64b_kernel(const float4* __restrict__ X4, const float4* __restrict__ W4,
                               const float4* __restrict__ bias4, float4* __restrict__ CB,
                               int n, int din4) {
    int k = blockIdx.y;
    const float4* Wk = W4 + (size_t)k * din4 * 64;
    float4* outk = CB + (size_t)k * n * 16;
    int t = threadIdx.x;
    int ot = t & 15;
    int nr = t >> 4;
    int nb = blockIdx.x * 64 + nr * 4;
    int ni[4];
#pragma unroll
    for (int i = 0; i < 4; ++i) ni[i] = min(nb + i, n - 1);
    float4 bv = {0.f, 0.f, 0.f, 0.f};
    if (k == 0 && bias4) bv = bias4[ot];
    float4 acc[4];
#pragma unroll
    for (int i = 0; i < 4; ++i) acc[i] = bv;
    for (int d4 = 0; d4 < din4; ++d4) {
        float4 xa[4];
#pragma unroll
        for (int i = 0; i < 4; ++i) xa[i] = X4[(size_t)ni[i] * din4 + d4];
        float4 wb[4];
#pragma unroll
        for (int j = 0; j < 4; ++j) wb[j] = Wk[(size_t)(d4 * 4 + j) * 16 + ot];
#pragma unroll
        for (int i = 0; i < 4; ++i) {
            const float xs[4] = {xa[i].x, xa[i].y, xa[i].z, xa[i].w};
#pragma unroll
            for (int j = 0; j < 4; ++j) {
                acc[i].x = fmaf(xs[j], wb[j].x, acc[i].x);
                acc[i].y = fmaf(xs[j], wb[j].y, acc[i].y);
                acc[i].z = fmaf(xs[j], wb[j].z, acc[i].z);
                acc[i].w = fmaf(xs[j], wb[j].w, acc[i].w);
            }
        }
    }
#pragma unroll
    for (int i = 0; i < 4; ++i)
        if (nb + i < n) outk[(size_t)(nb + i) * 16 + ot] = acc[i];
}

// ---------------- accumulate GEMM (layer-1 fallback path, round-4 style) ----------------
__global__ void gemm64_kernel(const float4* __restrict__ X4, const float4* __restrict__ W4,
                              const float4* __restrict__ bias4, float4* __restrict__ out4,
                              int n, int din4, int first, int bnrelu,
                              const float4* __restrict__ bn_g4, const float4* __restrict__ bn_b4,
                              const float4* __restrict__ bn_m4, const float4* __restrict__ bn_v4) {
    int t = threadIdx.x;
    int ot = t & 15;
    int nr = t >> 4;
    int nb = blockIdx.x * 64 + nr * 4;
    int ni[4];
#pragma unroll
    for (int i = 0; i < 4; ++i) ni[i] = min(nb + i, n - 1);
    float4 bv = {0.f, 0.f, 0.f, 0.f};
    if (bias4) bv = bias4[ot];
    float4 acc[4];
#pragma unroll
    for (int i = 0; i < 4; ++i) {
        if (first) acc[i] = bv;
        else {
            acc[i] = out4[(size_t)ni[i] * 16 + ot];
            acc[i].x += bv.x; acc[i].y += bv.y; acc[i].z += bv.z; acc[i].w += bv.w;
        }
    }
    for (int d4 = 0; d4 < din4; ++d4) {
        float4 xa[4];
#pragma unroll
        for (int i = 0; i < 4; ++i) xa[i] = X4[(size_t)ni[i] * din4 + d4];
        float4 wb[4];
#pragma unroll
        for (int j = 0; j < 4; ++j) wb[j] = W4[(size_t)(d4 * 4 + j) * 16 + ot];
#pragma unroll
        for (int i = 0; i < 4; ++i) {
            const float xs[4] = {xa[i].x, xa[i].y, xa[i].z, xa[i].w};
#pragma unroll
            for (int j = 0; j < 4; ++j) {
                acc[i].x = fmaf(xs[j], wb[j].x, acc[i].x);
                acc[i].y = fmaf(xs[j], wb[j].y, acc[i].y);
                acc[i].z = fmaf(xs[j], wb[j].z, acc[i].z);
                acc[i].w = fmaf(xs[j], wb[j].w, acc[i].w);
            }
        }
    }
    if (bnrelu) {
        float4 g = bn_g4[ot], b = bn_b4[ot], m = bn_m4[ot], v = bn_v4[ot];
        float4 sc;
        sc.x = g.x * rsqrtf(v.x + BN_EPS); sc.y = g.y * rsqrtf(v.y + BN_EPS);
        sc.z = g.z * rsqrtf(v.z + BN_EPS); sc.w = g.w * rsqrtf(v.w + BN_EPS);
#pragma unroll
        for (int i = 0; i < 4; ++i) {
            acc[i].x = fmaxf(fmaf(acc[i].x - m.x, sc.x, b.x), 0.f);
            acc[i].y = fmaxf(fmaf(acc[i].y - m.y, sc.y, b.y), 0.f);
            acc[i].z = fmaxf(fmaf(acc[i].z - m.z, sc.z, b.z), 0.f);
            acc[i].w = fmaxf(fmaf(acc[i].w - m.w, sc.w, b.w), 0.f);
        }
    }
#pragma unroll
    for (int i = 0; i < 4; ++i)
        if (nb + i < n) out4[(size_t)(nb + i) * 16 + ot] = acc[i];
}

// ---------------- batched small GEMM into K padded slices ----------------
template <int DOUT, int STRIDE>
__global__ void gemm_smallp_kernel(const float* __restrict__ X, int xstride, int din,
                                   const float* __restrict__ W, const float* __restrict__ bias,
                                   float* __restrict__ CB, int n) {
    int k = blockIdx.y;
    const float* Wk = W + (size_t)k * din * DOUT;
    float* outk = CB + (size_t)k * n * STRIDE;
    int t = blockIdx.x * blockDim.x + threadIdx.x;
    int nb = t * 4;
    if (nb >= n) return;
    int ni[4];
#pragma unroll
    for (int i = 0; i < 4; ++i) ni[i] = min(nb + i, n - 1);

    float acc[4][DOUT];
#pragma unroll
    for (int o = 0; o < DOUT; ++o) {
        float bv = (k == 0 && bias) ? bias[o] : 0.f;
#pragma unroll
        for (int i = 0; i < 4; ++i) acc[i][o] = bv;
    }

    if ((din & 3) == 0 && (xstride & 3) == 0) {
        int din4 = din >> 2, xs4 = xstride >> 2;
        const float4* X4 = reinterpret_cast<const float4*>(X);
        for (int d4 = 0; d4 < din4; ++d4) {
            float xs[4][4];
#pragma unroll
            for (int i = 0; i < 4; ++i) {
                float4 xv = X4[(size_t)ni[i] * xs4 + d4];
                xs[i][0] = xv.x; xs[i][1] = xv.y; xs[i][2] = xv.z; xs[i][3] = xv.w;
            }
#pragma unroll
            for (int j = 0; j < 4; ++j) {
                int dd = d4 * 4 + j;
#pragma unroll
                for (int o = 0; o < DOUT; ++o) {
                    float w = Wk[(size_t)dd * DOUT + o];
                    acc[0][o] = fmaf(xs[0][j], w, acc[0][o]);
                    acc[1][o] = fmaf(xs[1][j], w, acc[1][o]);
                    acc[2][o] = fmaf(xs[2][j], w, acc[2][o]);
                    acc[3][o] = fmaf(xs[3][j], w, acc[3][o]);
                }
            }
        }
    } else {
        for (int d = 0; d < din; ++d) {
            float x0 = X[(size_t)ni[0] * xstride + d];
            float x1 = X[(size_t)ni[1] * xstride + d];
            float x2 = X[(size_t)ni[2] * xstride + d];
            float x3 = X[(size_t)ni[3] * xstride + d];
#pragma unroll
            for (int o = 0; o < DOUT; ++o) {
                float w = Wk[(size_t)d * DOUT + o];
                acc[0][o] = fmaf(x0, w, acc[0][o]);
                acc[1][o] = fmaf(x1, w, acc[1][o]);
                acc[2][o] = fmaf(x2, w, acc[2][o]);
                acc[3][o] = fmaf(x3, w, acc[3][o]);
            }
        }
    }
#pragma unroll
    for (int i = 0; i < 4; ++i)
        if (nb + i < n) {
#pragma unroll
            for (int o = 0; o < DOUT; ++o) outk[(size_t)(nb + i) * STRIDE + o] = acc[i][o];
#pragma unroll
            for (int o = DOUT; o < STRIDE; ++o) outk[(size_t)(nb + i) * STRIDE + o] = 0.f;
        }
}

// ---------------- host driver ----------------

extern "C" void kernel_launch(void* const* d_in, const int* in_sizes, int n_in,
                              void* d_out, int out_size, void* d_ws, size_t ws_size,
                              hipStream_t stream) {
    const float* x  = (const float*)d_in[0];
    const int*   ei = (const int*)d_in[1];
    const float* Wl[4] = {(const float*)d_in[2], (const float*)d_in[4],
                          (const float*)d_in[6], (const float*)d_in[8]};
    const float* bl[4] = {(const float*)d_in[3], (const float*)d_in[5],
                          (const float*)d_in[7], (const float*)d_in[9]};
    const float* bn[3][4];
    for (int l = 0; l < 3; ++l)
        for (int j = 0; j < 4; ++j)
            bn[l][j] = (const float*)d_in[10 + 4 * l + j];

    char* ws = (char*)d_ws;
    size_t off = 0;
    auto alloc = [&](size_t bytes) -> void* {
        void* p = (void*)(ws + off);
        off = (off + bytes + 255) & ~(size_t)255;
        return p;
    };
    int*   deg     = (int*)alloc(NN * 4);
    int*   row_ptr = (int*)alloc((NN + 1) * 4);
    int*   cursor  = (int*)alloc(NN * 4);
    int*   blks    = (int*)alloc(128 * 4);
    float* dinv    = (float*)alloc(NN * 4);
    int2*  cw      = (int2*)alloc((size_t)NE * 8);
    float* B1      = (float*)alloc((size_t)NN * 64 * 4);
    float* B2      = (float*)alloc((size_t)NN * 64 * 4);
    float* B3      = (float*)alloc((size_t)NN * 64 * 4);
    float* B4      = (float*)alloc((size_t)NN * 20 * 4);
    float* CBs     = (float*)alloc((size_t)6 * NN * 20 * 4);   // small-layer C slices
    // layer-1 C slices only if workspace allows (deterministic across calls)
    float* CB1 = nullptr;
    if (off + (size_t)8 * NN * 64 * 4 + 256 <= ws_size)
        CB1 = (float*)alloc((size_t)8 * NN * 64 * 4);

    const int* srcp = ei;
    const int* dstp = ei + NE;
    const int nscan = divup(NN, 1024);

    hipMemsetAsync(deg, 0, NN * 4, stream);
    hipMemsetAsync(cursor, 0, NN * 4, stream);
    hist_kernel<<<divup(NE, 256), 256, 0, stream>>>(dstp, deg, NE);
    blksum_kernel<<<nscan, 256, 0, stream>>>(deg, blks, NN);
    blkscan_kernel<<<1, 256, 0, stream>>>(blks, nscan, row_ptr, NN);
    emit_kernel<<<nscan, 256, 0, stream>>>(deg, blks, row_ptr, NN);
    dinv_kernel<<<divup(NN, 256), 256, 0, stream>>>(deg, dinv, NN);
    scatter_kernel<<<divup(NE, 256), 256, 0, stream>>>(srcp, dstp, row_ptr, cursor, dinv, cw, NE);

    auto prop = [&](const float* feat, const float* sub, const float* add, float* out,
                    int dim4, float scale, int bnrelu, int used,
                    const float* g, const float* bb, const float* m, const float* v) {
        prop4f_kernel<<<divup(NN * dim4, 256), 256, 0, stream>>>(
            (const float4*)feat, (const float4*)sub, (const float4*)add, (float4*)out,
            row_ptr, cw, NN, dim4, scale, sub != nullptr, add != nullptr,
            bnrelu, used, g, bb, m, v);
    };

    // ---- layer 1 (din=128, dout=64, K=8) -> H1 = B1 ----
    if (CB1) {
        gemm64b_kernel<<<dim3(divup(NN, 64), 8), 256, 0, stream>>>(
            (const float4*)x, (const float4*)Wl[0], (const float4*)bl[0],
            (float4*)CB1, NN, 32);
        float* pool[3] = {B1, B2, B3};
        const float* b1 = CB1 + (size_t)7 * NN * 64;
        const float* b2 = nullptr;
        for (int s = 0; s < 6; ++s) {
            int k = 6 - s;
            float* tmp = pool[s % 3];
            prop(b1, b2, CB1 + (size_t)k * NN * 64, tmp, 16, 2.f, 0, 64,
                 nullptr, nullptr, nullptr, nullptr);
            b2 = b1; b1 = tmp;
        }
        prop(b1, b2, CB1, B1, 16, 1.f, 1, 64, bn[0][0], bn[0][1], bn[0][2], bn[0][3]);
    } else {
        // fallback: accumulate-GEMM Clenshaw (no C slices)
        gemm64_kernel<<<divup(NN, 64), 256, 0, stream>>>(
            (const float4*)x, (const float4*)(Wl[0] + (size_t)7 * 128 * 64), nullptr,
            (float4*)B3, NN, 32, 1, 0, nullptr, nullptr, nullptr, nullptr);
        float* pool[3] = {B1, B2, B3};
        const float* b1 = B3;
        const float* b2 = nullptr;
        for (int s = 0; s < 6; ++s) {
            int k = 6 - s;
            float* tmp = pool[s % 3];
            prop(b1, b2, nullptr, tmp, 16, 2.f, 0, 64, nullptr, nullptr, nullptr, nullptr);
            gemm64_kernel<<<divup(NN, 64), 256, 0, stream>>>(
                (const float4*)x, (const float4*)(Wl[0] + (size_t)k * 128 * 64), nullptr,
                (float4*)tmp, NN, 32, 0, 0, nullptr, nullptr, nullptr, nullptr);
            b2 = b1; b1 = tmp;
        }
        prop(b1, b2, nullptr, B1, 16, 1.f, 0, 64, nullptr, nullptr, nullptr, nullptr);
        gemm64_kernel<<<divup(NN, 64), 256, 0, stream>>>(
            (const float4*)x, (const float4*)Wl[0], (const float4*)bl[0],
            (float4*)B1, NN, 32, 0, 1,
            (const float4*)bn[0][0], (const float4*)bn[0][1],
            (const float4*)bn[0][2], (const float4*)bn[0][3]);
    }

    // ---- layer 2 (din=64, dout=18 pad 20, K=6): X=B1, pool {B2,B3,B4} -> H2 = B3 ----
    gemm_smallp_kernel<18, 20><<<dim3(divup(NN, 1024), 6), 256, 0, stream>>>(
        B1, 64, 64, Wl[1], bl[1], CBs, NN);
    {
        float* pool[3] = {B2, B3, B4};
        const float* b1 = CBs + (size_t)5 * NN * 20;
        const float* b2 = nullptr;
        for (int s = 0; s < 4; ++s) {
            int k = 4 - s;
            float* tmp = pool[s % 3];
            prop(b1, b2, CBs + (size_t)k * NN * 20, tmp, 5, 2.f, 0, 18,
                 nullptr, nullptr, nullptr, nullptr);
            b2 = b1; b1 = tmp;
        }
        prop(b1, b2, CBs, B3, 5, 1.f, 1, 18, bn[1][0], bn[1][1], bn[1][2], bn[1][3]);
    }

    // ---- layer 3 (din=18 stride 20, dout=9 pad 12, K=4): X=B3, pool {B2,B4} -> H3 = B1 ----
    gemm_smallp_kernel<9, 12><<<dim3(divup(NN, 1024), 4), 256, 0, stream>>>(
        B3, 20, 18, Wl[2], bl[2], CBs, NN);
    {
        const float* b1 = CBs + (size_t)3 * NN * 12;
        const float* b2 = nullptr;
        prop(b1, b2, CBs + (size_t)2 * NN * 12, B2, 3, 2.f, 0, 9, nullptr, nullptr, nullptr, nullptr);
        b2 = b1; b1 = B2;
        prop(b1, b2, CBs + (size_t)1 * NN * 12, B4, 3, 2.f, 0, 9, nullptr, nullptr, nullptr, nullptr);
        b2 = b1; b1 = B4;
        prop(b1, b2, CBs, B1, 3, 1.f, 1, 9, bn[2][0], bn[2][1], bn[2][2], bn[2][3]);
    }

    // ---- layer 4 (din=9 stride 12, dout=10 pad 12, K=4): X=B1 -> d_out ----
    gemm_smallp_kernel<10, 12><<<dim3(divup(NN, 1024), 4), 256, 0, stream>>>(
        B1, 12, 9, Wl[3], bl[3], CBs, NN);
    {
        const float* b1 = CBs + (size_t)3 * NN * 12;
        const float* b2 = nullptr;
        prop(b1, b2, CBs + (size_t)2 * NN * 12, B2, 3, 2.f, 0, 10, nullptr, nullptr, nullptr, nullptr);
        b2 = b1; b1 = B2;
        prop(b1, b2, CBs + (size_t)1 * NN * 12, B4, 3, 2.f, 0, 10, nullptr, nullptr, nullptr, nullptr);
        b2 = b1; b1 = B4;
        propl_kernel<<<divup(NN * 10, 256), 256, 0, stream>>>(
            b1, b2, CBs, (float*)d_out, row_ptr, cw, NN);
    }
}

// Round 6
// 1651.893 us; speedup vs baseline: 3.1958x; 1.0259x over previous
//
#include <hip/hip_runtime.h>

#define NN 100000
#define NE 1600000
#define BN_EPS 1e-5f

typedef _Float16 half1;
typedef _Float16 half4 __attribute__((ext_vector_type(4)));

static inline int divup(int a, int b) { return (a + b - 1) / b; }

// ---------------- preprocessing ----------------

__global__ void hist_kernel(const int* __restrict__ dst, int* __restrict__ deg, int e) {
    int i = blockIdx.x * blockDim.x + threadIdx.x;
    if (i < e) atomicAdd(&deg[dst[i]], 1);
}

__global__ void blksum_kernel(const int* __restrict__ deg, int* __restrict__ blk, int n) {
    __shared__ int red[256];
    int t = threadIdx.x;
    int base = blockIdx.x * 1024 + t * 4;
    int s = 0;
#pragma unroll
    for (int i = 0; i < 4; ++i) {
        int idx = base + i;
        if (idx < n) s += deg[idx];
    }
    red[t] = s;
    __syncthreads();
    for (int off = 128; off > 0; off >>= 1) {
        if (t < off) red[t] += red[t + off];
        __syncthreads();
    }
    if (t == 0) blk[blockIdx.x] = red[0];
}

__global__ void blkscan_kernel(int* __restrict__ blk, int nb, int* __restrict__ row_ptr, int n) {
    __shared__ int sh[256];
    int t = threadIdx.x;
    int v = (t < nb) ? blk[t] : 0;
    sh[t] = v;
    __syncthreads();
    for (int off = 1; off < 256; off <<= 1) {
        int u = (t >= off) ? sh[t - off] : 0;
        __syncthreads();
        sh[t] += u;
        __syncthreads();
    }
    if (t < nb) blk[t] = (t == 0) ? 0 : sh[t - 1];
    if (t == nb - 1) row_ptr[n] = sh[t];
}

__global__ void emit_kernel(const int* __restrict__ deg, const int* __restrict__ blk,
                            int* __restrict__ row_ptr, int n) {
    __shared__ int red[256];
    int t = threadIdx.x;
    int base = blockIdx.x * 1024 + t * 4;
    int d[4];
    int s = 0;
#pragma unroll
    for (int i = 0; i < 4; ++i) {
        int idx = base + i;
        d[i] = (idx < n) ? deg[idx] : 0;
        s += d[i];
    }
    red[t] = s;
    __syncthreads();
    for (int off = 1; off < 256; off <<= 1) {
        int u = (t >= off) ? red[t - off] : 0;
        __syncthreads();
        red[t] += u;
        __syncthreads();
    }
    int run = blk[blockIdx.x] + ((t == 0) ? 0 : red[t - 1]);
#pragma unroll
    for (int i = 0; i < 4; ++i) {
        int idx = base + i;
        if (idx < n) { row_ptr[idx] = run; run += d[i]; }
    }
}

__global__ void dinv_kernel(const int* __restrict__ deg, float* __restrict__ dinv, int n) {
    int i = blockIdx.x * blockDim.x + threadIdx.x;
    if (i < n) {
        int d = deg[i];
        dinv[i] = (d > 0) ? rsqrtf((float)d) : 0.f;
    }
}

__global__ void scatter_kernel(const int* __restrict__ src, const int* __restrict__ dst,
                               const int* __restrict__ row_ptr, int* __restrict__ cursor,
                               const float* __restrict__ dinv,
                               int2* __restrict__ cw, int e) {
    int i = blockIdx.x * blockDim.x + threadIdx.x;
    if (i >= e) return;
    int s = src[i], d = dst[i];
    int pos = row_ptr[d] + atomicAdd(&cursor[d], 1);
    cw[pos] = make_int2(s, __float_as_int(-dinv[s] * dinv[d]));
}

// ---------------- fused Clenshaw prop, fp32 gather (fallback path) ----------------
__global__ void prop4f_kernel(const float4* __restrict__ feat, const float4* __restrict__ sub,
                              const float4* __restrict__ add, float4* __restrict__ out,
                              const int* __restrict__ row_ptr, const int2* __restrict__ cw,
                              int n, int dim4, float scale, int has_sub, int has_add,
                              int bnrelu, int used,
                              const float* __restrict__ bn_g, const float* __restrict__ bn_b,
                              const float* __restrict__ bn_m, const float* __restrict__ bn_v) {
    int idx = blockIdx.x * blockDim.x + threadIdx.x;
    if (idx >= n * dim4) return;
    int nd = idx / dim4;
    int f = idx - nd * dim4;
    int e0 = row_ptr[nd], e1 = row_ptr[nd + 1];
    float4 a0 = {0.f, 0.f, 0.f, 0.f}, a1 = a0, a2 = a0, a3 = a0;
    int e = e0;
    for (; e + 4 <= e1; e += 4) {
        int2 q0 = cw[e], q1 = cw[e + 1], q2 = cw[e + 2], q3 = cw[e + 3];
        float4 v0 = feat[(size_t)q0.x * dim4 + f];
        float4 v1 = feat[(size_t)q1.x * dim4 + f];
        float4 v2 = feat[(size_t)q2.x * dim4 + f];
        float4 v3 = feat[(size_t)q3.x * dim4 + f];
        float w0 = __int_as_float(q0.y), w1 = __int_as_float(q1.y);
        float w2 = __int_as_float(q2.y), w3 = __int_as_float(q3.y);
        a0.x = fmaf(w0, v0.x, a0.x); a0.y = fmaf(w0, v0.y, a0.y);
        a0.z = fmaf(w0, v0.z, a0.z); a0.w = fmaf(w0, v0.w, a0.w);
        a1.x = fmaf(w1, v1.x, a1.x); a1.y = fmaf(w1, v1.y, a1.y);
        a1.z = fmaf(w1, v1.z, a1.z); a1.w = fmaf(w1, v1.w, a1.w);
        a2.x = fmaf(w2, v2.x, a2.x); a2.y = fmaf(w2, v2.y, a2.y);
        a2.z = fmaf(w2, v2.z, a2.z); a2.w = fmaf(w2, v2.w, a2.w);
        a3.x = fmaf(w3, v3.x, a3.x); a3.y = fmaf(w3, v3.y, a3.y);
        a3.z = fmaf(w3, v3.z, a3.z); a3.w = fmaf(w3, v3.w, a3.w);
    }
    for (; e < e1; ++e) {
        int2 q = cw[e];
        float w = __int_as_float(q.y);
        float4 v = feat[(size_t)q.x * dim4 + f];
        a0.x = fmaf(w, v.x, a0.x); a0.y = fmaf(w, v.y, a0.y);
        a0.z = fmaf(w, v.z, a0.z); a0.w = fmaf(w, v.w, a0.w);
    }
    float r[4];
    r[0] = ((a0.x + a1.x) + (a2.x + a3.x)) * scale;
    r[1] = ((a0.y + a1.y) + (a2.y + a3.y)) * scale;
    r[2] = ((a0.z + a1.z) + (a2.z + a3.z)) * scale;
    r[3] = ((a0.w + a1.w) + (a2.w + a3.w)) * scale;
    if (has_sub) {
        float4 s4 = sub[idx];
        r[0] -= s4.x; r[1] -= s4.y; r[2] -= s4.z; r[3] -= s4.w;
    }
    if (has_add) {
        float4 c4 = add[idx];
        r[0] += c4.x; r[1] += c4.y; r[2] += c4.z; r[3] += c4.w;
    }
    if (bnrelu) {
#pragma unroll
        for (int c = 0; c < 4; ++c) {
            int o = f * 4 + c;
            if (o < used) {
                float sc = bn_g[o] * rsqrtf(bn_v[o] + BN_EPS);
                r[c] = fmaxf(fmaf(r[c] - bn_m[o], sc, bn_b[o]), 0.f);
            } else r[c] = 0.f;
        }
    }
    out[idx] = make_float4(r[0], r[1], r[2], r[3]);
}

// ---------------- fused Clenshaw prop, fp16 gather + optional fp16 shadow out ----------
__global__ void prop4h_kernel(const half4* __restrict__ feat_h, const float4* __restrict__ sub,
                              const float4* __restrict__ add, float4* __restrict__ out,
                              half4* __restrict__ out_h,
                              const int* __restrict__ row_ptr, const int2* __restrict__ cw,
                              int n, int dim4, float scale, int has_sub, int has_add,
                              int bnrelu, int used,
                              const float* __restrict__ bn_g, const float* __restrict__ bn_b,
                              const float* __restrict__ bn_m, const float* __restrict__ bn_v) {
    int idx = blockIdx.x * blockDim.x + threadIdx.x;
    if (idx >= n * dim4) return;
    int nd = idx / dim4;
    int f = idx - nd * dim4;
    int e0 = row_ptr[nd], e1 = row_ptr[nd + 1];
    float4 a0 = {0.f, 0.f, 0.f, 0.f}, a1 = a0, a2 = a0, a3 = a0;
    int e = e0;
    for (; e + 4 <= e1; e += 4) {
        int2 q0 = cw[e], q1 = cw[e + 1], q2 = cw[e + 2], q3 = cw[e + 3];
        half4 h0 = feat_h[(size_t)q0.x * dim4 + f];
        half4 h1 = feat_h[(size_t)q1.x * dim4 + f];
        half4 h2 = feat_h[(size_t)q2.x * dim4 + f];
        half4 h3 = feat_h[(size_t)q3.x * dim4 + f];
        float w0 = __int_as_float(q0.y), w1 = __int_as_float(q1.y);
        float w2 = __int_as_float(q2.y), w3 = __int_as_float(q3.y);
        a0.x = fmaf((float)h0.x, w0, a0.x); a0.y = fmaf((float)h0.y, w0, a0.y);
        a0.z = fmaf((float)h0.z, w0, a0.z); a0.w = fmaf((float)h0.w, w0, a0.w);
        a1.x = fmaf((float)h1.x, w1, a1.x); a1.y = fmaf((float)h1.y, w1, a1.y);
        a1.z = fmaf((float)h1.z, w1, a1.z); a1.w = fmaf((float)h1.w, w1, a1.w);
        a2.x = fmaf((float)h2.x, w2, a2.x); a2.y = fmaf((float)h2.y, w2, a2.y);
        a2.z = fmaf((float)h2.z, w2, a2.z); a2.w = fmaf((float)h2.w, w2, a2.w);
        a3.x = fmaf((float)h3.x, w3, a3.x); a3.y = fmaf((float)h3.y, w3, a3.y);
        a3.z = fmaf((float)h3.z, w3, a3.z); a3.w = fmaf((float)h3.w, w3, a3.w);
    }
    for (; e < e1; ++e) {
        int2 q = cw[e];
        float w = __int_as_float(q.y);
        half4 h = feat_h[(size_t)q.x * dim4 + f];
        a0.x = fmaf((float)h.x, w, a0.x); a0.y = fmaf((float)h.y, w, a0.y);
        a0.z = fmaf((float)h.z, w, a0.z); a0.w = fmaf((float)h.w, w, a0.w);
    }
    float r[4];
    r[0] = ((a0.x + a1.x) + (a2.x + a3.x)) * scale;
    r[1] = ((a0.y + a1.y) + (a2.y + a3.y)) * scale;
    r[2] = ((a0.z + a1.z) + (a2.z + a3.z)) * scale;
    r[3] = ((a0.w + a1.w) + (a2.w + a3.w)) * scale;
    if (has_sub) {
        float4 s4 = sub[idx];
        r[0] -= s4.x; r[1] -= s4.y; r[2] -= s4.z; r[3] -= s4.w;
    }
    if (has_add) {
        float4 c4 = add[idx];
        r[0] += c4.x; r[1] += c4.y; r[2] += c4.z; r[3] += c4.w;
    }
    if (bnrelu) {
#pragma unroll
        for (int c = 0; c < 4; ++c) {
            int o = f * 4 + c;
            if (o < used) {
                float sc = bn_g[o] * rsqrtf(bn_v[o] + BN_EPS);
                r[c] = fmaxf(fmaf(r[c] - bn_m[o], sc, bn_b[o]), 0.f);
            } else r[c] = 0.f;
        }
    }
    out[idx] = make_float4(r[0], r[1], r[2], r[3]);
    if (out_h) {
        half4 hh;
        hh.x = (half1)r[0]; hh.y = (half1)r[1]; hh.z = (half1)r[2]; hh.w = (half1)r[3];
        out_h[idx] = hh;
    }
}

// layer-4 final, fp32 gather (fallback): feat/sub/add stride 12, out stride 10
__global__ void propl_kernel(const float* __restrict__ feat, const float* __restrict__ sub,
                             const float* __restrict__ add, float* __restrict__ out,
                             const int* __restrict__ row_ptr, const int2* __restrict__ cw, int n) {
    int idx = blockIdx.x * blockDim.x + threadIdx.x;
    if (idx >= n * 10) return;
    int nd = idx / 10;
    int o = idx - nd * 10;
    int e0 = row_ptr[nd], e1 = row_ptr[nd + 1];
    float a0 = 0.f, a1 = 0.f, a2 = 0.f, a3 = 0.f;
    int e = e0;
    for (; e + 4 <= e1; e += 4) {
        int2 q0 = cw[e], q1 = cw[e + 1], q2 = cw[e + 2], q3 = cw[e + 3];
        a0 = fmaf(__int_as_float(q0.y), feat[(size_t)q0.x * 12 + o], a0);
        a1 = fmaf(__int_as_float(q1.y), feat[(size_t)q1.x * 12 + o], a1);
        a2 = fmaf(__int_as_float(q2.y), feat[(size_t)q2.x * 12 + o], a2);
        a3 = fmaf(__int_as_float(q3.y), feat[(size_t)q3.x * 12 + o], a3);
    }
    for (; e < e1; ++e) {
        int2 q = cw[e];
        a0 = fmaf(__int_as_float(q.y), feat[(size_t)q.x * 12 + o], a0);
    }
    float acc = (a0 + a1) + (a2 + a3);
    out[idx] = acc - sub[(size_t)nd * 12 + o] + add[(size_t)nd * 12 + o];
}

// layer-4 final, fp16 gather
__global__ void proplh_kernel(const half1* __restrict__ feat_h, const float* __restrict__ sub,
                              const float* __restrict__ add, float* __restrict__ out,
                              const int* __restrict__ row_ptr, const int2* __restrict__ cw, int n) {
    int idx = blockIdx.x * blockDim.x + threadIdx.x;
    if (idx >= n * 10) return;
    int nd = idx / 10;
    int o = idx - nd * 10;
    int e0 = row_ptr[nd], e1 = row_ptr[nd + 1];
    float a0 = 0.f, a1 = 0.f, a2 = 0.f, a3 = 0.f;
    int e = e0;
    for (; e + 4 <= e1; e += 4) {
        int2 q0 = cw[e], q1 = cw[e + 1], q2 = cw[e + 2], q3 = cw[e + 3];
        a0 = fmaf(__int_as_float(q0.y), (float)feat_h[(size_t)q0.x * 12 + o], a0);
        a1 = fmaf(__int_as_float(q1.y), (float)feat_h[(size_t)q1.x * 12 + o], a1);
        a2 = fmaf(__int_as_float(q2.y), (float)feat_h[(size_t)q2.x * 12 + o], a2);
        a3 = fmaf(__int_as_float(q3.y), (float)feat_h[(size_t)q3.x * 12 + o], a3);
    }
    for (; e < e1; ++e) {
        int2 q = cw[e];
        a0 = fmaf(__int_as_float(q.y), (float)feat_h[(size_t)q.x * 12 + o], a0);
    }
    float acc = (a0 + a1) + (a2 + a3);
    out[idx] = acc - sub[(size_t)nd * 12 + o] + add[(size_t)nd * 12 + o];
}

// ---------------- batched GEMM, 2 k-slices per block (layer 1, dout=64) --------------
// writes fp16 shadow of slice k==7 when SH != null
__global__ void gemm64b2_kernel(const float4* __restrict__ X4, const float4* __restrict__ W4,
                                const float4* __restrict__ bias4, float4* __restrict__ CB,
                                half4* __restrict__ SH, int n, int din4) {
    int k0 = blockIdx.y * 2;
    int din = din4 * 4;
    int t = threadIdx.x;
    int ot = t & 15;
    int nr = t >> 4;
    int nb = blockIdx.x * 64 + nr * 4;
    int ni[4];
#pragma unroll
    for (int i = 0; i < 4; ++i) ni[i] = min(nb + i, n - 1);

    float4 acc[2][4];
#pragma unroll
    for (int kk = 0; kk < 2; ++kk) {
        float4 bv = {0.f, 0.f, 0.f, 0.f};
        if (k0 + kk == 0 && bias4) bv = bias4[ot];
#pragma unroll
        for (int i = 0; i < 4; ++i) acc[kk][i] = bv;
    }

    for (int d4 = 0; d4 < din4; ++d4) {
        float4 xa[4];
#pragma unroll
        for (int i = 0; i < 4; ++i) xa[i] = X4[(size_t)ni[i] * din4 + d4];
        float4 wb[2][4];
#pragma unroll
        for (int kk = 0; kk < 2; ++kk)
#pragma unroll
            for (int j = 0; j < 4; ++j)
                wb[kk][j] = W4[((size_t)(k0 + kk) * din + d4 * 4 + j) * 16 + ot];
#pragma unroll
        for (int i = 0; i < 4; ++i) {
            const float xs[4] = {xa[i].x, xa[i].y, xa[i].z, xa[i].w};
#pragma unroll
            for (int kk = 0; kk < 2; ++kk)
#pragma unroll
                for (int j = 0; j < 4; ++j) {
                    acc[kk][i].x = fmaf(xs[j], wb[kk][j].x, acc[kk][i].x);
                    acc[kk][i].y = fmaf(xs[j], wb[kk][j].y, acc[kk][i].y);
                    acc[kk][i].z = fmaf(xs[j], wb[kk][j].z, acc[kk][i].z);
                    acc[kk][i].w = fmaf(xs[j], wb[kk][j].w, acc[kk][i].w);
                }
        }
    }
#pragma unroll
    for (int kk = 0; kk < 2; ++kk)
#pragma unroll
        for (int i = 0; i < 4; ++i)
            if (nb + i < n) {
                CB[((size_t)(k0 + kk) * n + nb + i) * 16 + ot] = acc[kk][i];
                if (SH && (k0 + kk) == 7) {
                    half4 hh;
                    hh.x = (half1)acc[kk][i].x; hh.y = (half1)acc[kk][i].y;
                    hh.z = (half1)acc[kk][i].z; hh.w = (half1)acc[kk][i].w;
                    SH[(size_t)(nb + i) * 16 + ot] = hh;
                }
            }
}

// ---------------- accumulate GEMM (deep-fallback layer-1 path) ----------------
__global__ void gemm64_kernel(const float4* __restrict__ X4, const float4* __restrict__ W4,
                              const float4* __restrict__ bias4, float4* __restrict__ out4,
                              int n, int din4, int first, int bnrelu,
                              const float4* __restrict__ bn_g4, const float4* __restrict__ bn_b4,
                              const float4* __restrict__ bn_m4, const float4* __restrict__ bn_v4) {
    int t = threadIdx.x;
    int ot = t & 15;
    int nr = t >> 4;
    int nb = blockIdx.x * 64 + nr * 4;
    int ni[4];
#pragma unroll
    for (int i = 0; i < 4; ++i) ni[i] = min(nb + i, n - 1);
    float4 bv = {0.f, 0.f, 0.f, 0.f};
    if (bias4) bv = bias4[ot];
    float4 acc[4];
#pragma unroll
    for (int i = 0; i < 4; ++i) {
        if (first) acc[i] = bv;
        else {
            acc[i] = out4[(size_t)ni[i] * 16 + ot];
            acc[i].x += bv.x; acc[i].y += bv.y; acc[i].z += bv.z; acc[i].w += bv.w;
        }
    }
    for (int d4 = 0; d4 < din4; ++d4) {
        float4 xa[4];
#pragma unroll
        for (int i = 0; i < 4; ++i) xa[i] = X4[(size_t)ni[i] * din4 + d4];
        float4 wb[4];
#pragma unroll
        for (int j = 0; j < 4; ++j) wb[j] = W4[(size_t)(d4 * 4 + j) * 16 + ot];
#pragma unroll
        for (int i = 0; i < 4; ++i) {
            const float xs[4] = {xa[i].x, xa[i].y, xa[i].z, xa[i].w};
#pragma unroll
            for (int j = 0; j < 4; ++j) {
                acc[i].x = fmaf(xs[j], wb[j].x, acc[i].x);
                acc[i].y = fmaf(xs[j], wb[j].y, acc[i].y);
                acc[i].z = fmaf(xs[j], wb[j].z, acc[i].z);
                acc[i].w = fmaf(xs[j], wb[j].w, acc[i].w);
            }
        }
    }
    if (bnrelu) {
        float4 g = bn_g4[ot], b = bn_b4[ot], m = bn_m4[ot], v = bn_v4[ot];
        float4 sc;
        sc.x = g.x * rsqrtf(v.x + BN_EPS); sc.y = g.y * rsqrtf(v.y + BN_EPS);
        sc.z = g.z * rsqrtf(v.z + BN_EPS); sc.w = g.w * rsqrtf(v.w + BN_EPS);
#pragma unroll
        for (int i = 0; i < 4; ++i) {
            acc[i].x = fmaxf(fmaf(acc[i].x - m.x, sc.x, b.x), 0.f);
            acc[i].y = fmaxf(fmaf(acc[i].y - m.y, sc.y, b.y), 0.f);
            acc[i].z = fmaxf(fmaf(acc[i].z - m.z, sc.z, b.z), 0.f);
            acc[i].w = fmaxf(fmaf(acc[i].w - m.w, sc.w, b.w), 0.f);
        }
    }
#pragma unroll
    for (int i = 0; i < 4; ++i)
        if (nb + i < n) out4[(size_t)(nb + i) * 16 + ot] = acc[i];
}

// ---------------- batched small GEMM into K padded slices, NPT nodes/thread ----------
// writes fp16 shadow of slice k == gridDim.y-1 when SH != null
template <int DOUT, int STRIDE, int NPT>
__global__ void gemm_smallp_kernel(const float* __restrict__ X, int xstride, int din,
                                   const float* __restrict__ W, const float* __restrict__ bias,
                                   float* __restrict__ CB, half1* __restrict__ SH, int n) {
    int k = blockIdx.y;
    int klast = gridDim.y - 1;
    const float* Wk = W + (size_t)k * din * DOUT;
    float* outk = CB + (size_t)k * n * STRIDE;
    int t = blockIdx.x * blockDim.x + threadIdx.x;
    int nb = t * NPT;
    if (nb >= n) return;
    int ni[NPT];
#pragma unroll
    for (int i = 0; i < NPT; ++i) ni[i] = min(nb + i, n - 1);

    float acc[NPT][DOUT];
#pragma unroll
    for (int o = 0; o < DOUT; ++o) {
        float bv = (k == 0 && bias) ? bias[o] : 0.f;
#pragma unroll
        for (int i = 0; i < NPT; ++i) acc[i][o] = bv;
    }

    if ((din & 3) == 0 && (xstride & 3) == 0) {
        int din4 = din >> 2, xs4 = xstride >> 2;
        const float4* X4 = reinterpret_cast<const float4*>(X);
        for (int d4 = 0; d4 < din4; ++d4) {
            float xs[NPT][4];
#pragma unroll
            for (int i = 0; i < NPT; ++i) {
                float4 xv = X4[(size_t)ni[i] * xs4 + d4];
                xs[i][0] = xv.x; xs[i][1] = xv.y; xs[i][2] = xv.z; xs[i][3] = xv.w;
            }
#pragma unroll
            for (int j = 0; j < 4; ++j) {
                int dd = d4 * 4 + j;
#pragma unroll
                for (int o = 0; o < DOUT; ++o) {
                    float w = Wk[(size_t)dd * DOUT + o];
#pragma unroll
                    for (int i = 0; i < NPT; ++i)
                        acc[i][o] = fmaf(xs[i][j], w, acc[i][o]);
                }
            }
        }
    } else {
        for (int d = 0; d < din; ++d) {
            float xs[NPT];
#pragma unroll
            for (int i = 0; i < NPT; ++i) xs[i] = X[(size_t)ni[i] * xstride + d];
#pragma unroll
            for (int o = 0; o < DOUT; ++o) {
                float w = Wk[(size_t)d * DOUT + o];
#pragma unroll
                for (int i = 0; i < NPT; ++i)
                    acc[i][o] = fmaf(xs[i], w, acc[i][o]);
            }
        }
    }
#pragma unroll
    for (int i = 0; i < NPT; ++i)
        if (nb + i < n) {
#pragma unroll
            for (int o = 0; o < DOUT; ++o) outk[(size_t)(nb + i) * STRIDE + o] = acc[i][o];
#pragma unroll
            for (int o = DOUT; o < STRIDE; ++o) outk[(size_t)(nb + i) * STRIDE + o] = 0.f;
            if (SH && k == klast) {
#pragma unroll
                for (int o = 0; o < DOUT; ++o)
                    SH[(size_t)(nb + i) * STRIDE + o] = (half1)acc[i][o];
#pragma unroll
                for (int o = DOUT; o < STRIDE; ++o)
                    SH[(size_t)(nb + i) * STRIDE + o] = (half1)0.f;
            }
        }
}

// ---------------- host driver ----------------

extern "C" void kernel_launch(void* const* d_in, const int* in_sizes, int n_in,
                              void* d_out, int out_size, void* d_ws, size_t ws_size,
                              hipStream_t stream) {
    const float* x  = (const float*)d_in[0];
    const int*   ei = (const int*)d_in[1];
    const float* Wl[4] = {(const float*)d_in[2], (const float*)d_in[4],
                          (const float*)d_in[6], (const float*)d_in[8]};
    const float* bl[4] = {(const float*)d_in[3], (const float*)d_in[5],
                          (const float*)d_in[7], (const float*)d_in[9]};
    const float* bn[3][4];
    for (int l = 0; l < 3; ++l)
        for (int j = 0; j < 4; ++j)
            bn[l][j] = (const float*)d_in[10 + 4 * l + j];

    char* ws = (char*)d_ws;
    size_t off = 0;
    auto alloc = [&](size_t bytes) -> void* {
        void* p = (void*)(ws + off);
        off = (off + bytes + 255) & ~(size_t)255;
        return p;
    };
    int*   deg     = (int*)alloc(NN * 4);
    int*   row_ptr = (int*)alloc((NN + 1) * 4);
    int*   cursor  = (int*)alloc(NN * 4);
    int*   blks    = (int*)alloc(128 * 4);
    float* dinv    = (float*)alloc(NN * 4);
    int2*  cw      = (int2*)alloc((size_t)NE * 8);
    float* P0      = (float*)alloc((size_t)NN * 64 * 4);
    float* P1      = (float*)alloc((size_t)NN * 64 * 4);
    float* P2      = (float*)alloc((size_t)NN * 64 * 4);
    float* P3      = (float*)alloc((size_t)NN * 20 * 4);
    float* CBs     = (float*)alloc((size_t)6 * NN * 20 * 4);
    size_t off_mark = off;                       // slow-path CB1 would start here
    half1* S0      = (half1*)alloc((size_t)NN * 64 * 2);
    half1* S1      = (half1*)alloc((size_t)NN * 64 * 2);
    half1* S2      = (half1*)alloc((size_t)NN * 64 * 2);
    half1* SHk     = (half1*)alloc((size_t)NN * 64 * 2);
    float* CB1     = (float*)alloc((size_t)8 * NN * 64 * 4);
    bool fast = (off <= ws_size);

    const int* srcp = ei;
    const int* dstp = ei + NE;
    const int nscan = divup(NN, 1024);

    hipMemsetAsync(deg, 0, NN * 4, stream);
    hipMemsetAsync(cursor, 0, NN * 4, stream);
    hist_kernel<<<divup(NE, 256), 256, 0, stream>>>(dstp, deg, NE);
    blksum_kernel<<<nscan, 256, 0, stream>>>(deg, blks, NN);
    blkscan_kernel<<<1, 256, 0, stream>>>(blks, nscan, row_ptr, NN);
    emit_kernel<<<nscan, 256, 0, stream>>>(deg, blks, row_ptr, NN);
    dinv_kernel<<<divup(NN, 256), 256, 0, stream>>>(deg, dinv, NN);
    scatter_kernel<<<divup(NE, 256), 256, 0, stream>>>(srcp, dstp, row_ptr, cursor, dinv, cw, NE);

    auto proph = [&](const half1* feat_h, const float* sub, const float* add,
                     float* out, half1* out_h, int dim4, float scale, int bnrelu, int used,
                     const float* g, const float* bb, const float* m, const float* v) {
        prop4h_kernel<<<divup(NN * dim4, 256), 256, 0, stream>>>(
            (const half4*)feat_h, (const float4*)sub, (const float4*)add, (float4*)out,
            (half4*)out_h, row_ptr, cw, NN, dim4, scale, sub != nullptr, add != nullptr,
            bnrelu, used, g, bb, m, v);
    };
    auto propf = [&](const float* feat, const float* sub, const float* add, float* out,
                     int dim4, float scale, int bnrelu, int used,
                     const float* g, const float* bb, const float* m, const float* v) {
        prop4f_kernel<<<divup(NN * dim4, 256), 256, 0, stream>>>(
            (const float4*)feat, (const float4*)sub, (const float4*)add, (float4*)out,
            row_ptr, cw, NN, dim4, scale, sub != nullptr, add != nullptr,
            bnrelu, used, g, bb, m, v);
    };

    if (fast) {
        // ======== fp16-gather Clenshaw path ========
        // ---- layer 1 (din=128, dout=64, K=8) -> H1 = P0 ----
        gemm64b2_kernel<<<dim3(divup(NN, 64), 4), 256, 0, stream>>>(
            (const float4*)x, (const float4*)Wl[0], (const float4*)bl[0],
            (float4*)CB1, (half4*)SHk, NN, 32);
        {
            float* poolf[3] = {P0, P1, P2};
            half1* poolh[3] = {S0, S1, S2};
            const float* b1f = CB1 + (size_t)7 * NN * 64;
            const half1* b1h = SHk;
            const float* b2f = nullptr;
            for (int s = 0; s < 6; ++s) {
                int k = 6 - s;
                proph(b1h, b2f, CB1 + (size_t)k * NN * 64, poolf[s % 3], poolh[s % 3],
                      16, 2.f, 0, 64, nullptr, nullptr, nullptr, nullptr);
                b2f = b1f; b1f = poolf[s % 3]; b1h = poolh[s % 3];
            }
            proph(b1h, b2f, CB1, P0, nullptr, 16, 1.f, 1, 64,
                  bn[0][0], bn[0][1], bn[0][2], bn[0][3]);
        }
        // ---- layer 2 (din=64, dout=18/20, K=6): X=P0 -> H2 = P2 ----
        gemm_smallp_kernel<18, 20, 2><<<dim3(divup(divup(NN, 2), 256), 6), 256, 0, stream>>>(
            P0, 64, 64, Wl[1], bl[1], CBs, SHk, NN);
        {
            float* poolf[3] = {P1, P2, P3};
            half1* poolh[3] = {S0, S1, S2};
            const float* b1f = CBs + (size_t)5 * NN * 20;
            const half1* b1h = SHk;
            const float* b2f = nullptr;
            for (int s = 0; s < 4; ++s) {
                proph(b1h, b2f, CBs + (size_t)(4 - s) * NN * 20, poolf[s % 3], poolh[s % 3],
                      5, 2.f, 0, 18, nullptr, nullptr, nullptr, nullptr);
                b2f = b1f; b1f = poolf[s % 3]; b1h = poolh[s % 3];
            }
            proph(b1h, b2f, CBs, P2, nullptr, 5, 1.f, 1, 18,
                  bn[1][0], bn[1][1], bn[1][2], bn[1][3]);
        }
        // ---- layer 3 (din=18 str20, dout=9/12, K=4): X=P2 -> H3 = P3 ----
        gemm_smallp_kernel<9, 12, 4><<<dim3(divup(divup(NN, 4), 256), 4), 256, 0, stream>>>(
            P2, 20, 18, Wl[2], bl[2], CBs, SHk, NN);
        {
            const float* b1f = CBs + (size_t)3 * NN * 12;
            const half1* b1h = SHk;
            const float* b2f = nullptr;
            proph(b1h, b2f, CBs + (size_t)2 * NN * 12, P0, S0, 3, 2.f, 0, 9,
                  nullptr, nullptr, nullptr, nullptr);
            b2f = b1f; b1f = P0; b1h = S0;
            proph(b1h, b2f, CBs + (size_t)1 * NN * 12, P1, S1, 3, 2.f, 0, 9,
                  nullptr, nullptr, nullptr, nullptr);
            b2f = b1f; b1f = P1; b1h = S1;
            proph(b1h, b2f, CBs, P3, nullptr, 3, 1.f, 1, 9,
                  bn[2][0], bn[2][1], bn[2][2], bn[2][3]);
        }
        // ---- layer 4 (din=9 str12, dout=10/12, K=4): X=P3 -> d_out ----
        gemm_smallp_kernel<10, 12, 4><<<dim3(divup(divup(NN, 4), 256), 4), 256, 0, stream>>>(
            P3, 12, 9, Wl[3], bl[3], CBs, SHk, NN);
        {
            const float* b1f = CBs + (size_t)3 * NN * 12;
            const half1* b1h = SHk;
            const float* b2f = nullptr;
            proph(b1h, b2f, CBs + (size_t)2 * NN * 12, P0, S0, 3, 2.f, 0, 10,
                  nullptr, nullptr, nullptr, nullptr);
            b2f = b1f; b1f = P0; b1h = S0;
            proph(b1h, b2f, CBs + (size_t)1 * NN * 12, P1, S1, 3, 2.f, 0, 10,
                  nullptr, nullptr, nullptr, nullptr);
            b2f = b1f; b1f = P1; b1h = S1;
            proplh_kernel<<<divup(NN * 10, 256), 256, 0, stream>>>(
                b1h, b2f, CBs, (float*)d_out, row_ptr, cw, NN);
        }
        return;
    }

    // ======== fp32 fallback (round-5 structure) ========
    float* CB1s = (float*)(ws + off_mark);
    bool have_cb1 = (off_mark + (size_t)8 * NN * 64 * 4 <= ws_size);

    // ---- layer 1 -> H1 = P0 ----
    if (have_cb1) {
        gemm64b2_kernel<<<dim3(divup(NN, 64), 4), 256, 0, stream>>>(
            (const float4*)x, (const float4*)Wl[0], (const float4*)bl[0],
            (float4*)CB1s, nullptr, NN, 32);
        float* poolf[3] = {P0, P1, P2};
        const float* b1f = CB1s + (size_t)7 * NN * 64;
        const float* b2f = nullptr;
        for (int s = 0; s < 6; ++s) {
            int k = 6 - s;
            propf(b1f, b2f, CB1s + (size_t)k * NN * 64, poolf[s % 3],
                  16, 2.f, 0, 64, nullptr, nullptr, nullptr, nullptr);
            b2f = b1f; b1f = poolf[s % 3];
        }
        propf(b1f, b2f, CB1s, P0, 16, 1.f, 1, 64, bn[0][0], bn[0][1], bn[0][2], bn[0][3]);
    } else {
        gemm64_kernel<<<divup(NN, 64), 256, 0, stream>>>(
            (const float4*)x, (const float4*)(Wl[0] + (size_t)7 * 128 * 64), nullptr,
            (float4*)P2, NN, 32, 1, 0, nullptr, nullptr, nullptr, nullptr);
        float* poolf[3] = {P0, P1, P2};
        const float* b1f = P2;
        const float* b2f = nullptr;
        for (int s = 0; s < 6; ++s) {
            int k = 6 - s;
            float* tmp = poolf[s % 3];
            propf(b1f, b2f, nullptr, tmp, 16, 2.f, 0, 64, nullptr, nullptr, nullptr, nullptr);
            gemm64_kernel<<<divup(NN, 64), 256, 0, stream>>>(
                (const float4*)x, (const float4*)(Wl[0] + (size_t)k * 128 * 64), nullptr,
                (float4*)tmp, NN, 32, 0, 0, nullptr, nullptr, nullptr, nullptr);
            b2f = b1f; b1f = tmp;
        }
        propf(b1f, b2f, nullptr, P0, 16, 1.f, 0, 64, nullptr, nullptr, nullptr, nullptr);
        gemm64_kernel<<<divup(NN, 64), 256, 0, stream>>>(
            (const float4*)x, (const float4*)Wl[0], (const float4*)bl[0],
            (float4*)P0, NN, 32, 0, 1,
            (const float4*)bn[0][0], (const float4*)bn[0][1],
            (const float4*)bn[0][2], (const float4*)bn[0][3]);
    }
    // ---- layer 2 -> H2 = P2 ----
    gemm_smallp_kernel<18, 20, 2><<<dim3(divup(divup(NN, 2), 256), 6), 256, 0, stream>>>(
        P0, 64, 64, Wl[1], bl[1], CBs, nullptr, NN);
    {
        float* poolf[3] = {P1, P2, P3};
        const float* b1f = CBs + (size_t)5 * NN * 20;
        const float* b2f = nullptr;
        for (int s = 0; s < 4; ++s) {
            propf(b1f, b2f, CBs + (size_t)(4 - s) * NN * 20, poolf[s % 3],
                  5, 2.f, 0, 18, nullptr, nullptr, nullptr, nullptr);
            b2f = b1f; b1f = poolf[s % 3];
        }
        propf(b1f, b2f, CBs, P2, 5, 1.f, 1, 18, bn[1][0], bn[1][1], bn[1][2], bn[1][3]);
    }
    // ---- layer 3 -> H3 = P3 ----
    gemm_smallp_kernel<9, 12, 4><<<dim3(divup(divup(NN, 4), 256), 4), 256, 0, stream>>>(
        P2, 20, 18, Wl[2], bl[2], CBs, nullptr, NN);
    {
        const float* b1f = CBs + (size_t)3 * NN * 12;
        const float* b2f = nullptr;
        propf(b1f, b2f, CBs + (size_t)2 * NN * 12, P0, 3, 2.f, 0, 9, nullptr, nullptr, nullptr, nullptr);
        b2f = b1f; b1f = P0;
        propf(b1f, b2f, CBs + (size_t)1 * NN * 12, P1, 3, 2.f, 0, 9, nullptr, nullptr, nullptr, nullptr);
        b2f = b1f; b1f = P1;
        propf(b1f, b2f, CBs, P3, 3, 1.f, 1, 9, bn[2][0], bn[2][1], bn[2][2], bn[2][3]);
    }
    // ---- layer 4 -> d_out ----
    gemm_smallp_kernel<10, 12, 4><<<dim3(divup(divup(NN, 4), 256), 4), 256, 0, stream>>>(
        P3, 12, 9, Wl[3], bl[3], CBs, nullptr, NN);
    {
        const float* b1f = CBs + (size_t)3 * NN * 12;
        const float* b2f = nullptr;
        propf(b1f, b2f, CBs + (size_t)2 * NN * 12, P0, 3, 2.f, 0, 10, nullptr, nullptr, nullptr, nullptr);
        b2f = b1f; b1f = P0;
        propf(b1f, b2f, CBs + (size_t)1 * NN * 12, P1, 3, 2.f, 0, 10, nullptr, nullptr, nullptr, nullptr);
        b2f = b1f; b1f = P1;
        propl_kernel<<<divup(NN * 10, 256), 256, 0, stream>>>(
            b1f, b2f, CBs, (float*)d_out, row_ptr, cw, NN);
    }
}

// Round 7
// 1023.096 us; speedup vs baseline: 5.1600x; 1.6146x over previous
//
#include <hip/hip_runtime.h>

#define NN 100000
#define NE 1600000
#define BN_EPS 1e-5f

typedef _Float16 half1;
typedef _Float16 half4 __attribute__((ext_vector_type(4)));
typedef float f4 __attribute__((ext_vector_type(4)));

static inline int divup(int a, int b) { return (a + b - 1) / b; }

// ---------------- preprocessing ----------------

__global__ void hist_kernel(const int* __restrict__ dst, int* __restrict__ deg, int e) {
    int i = blockIdx.x * blockDim.x + threadIdx.x;
    if (i < e) atomicAdd(&deg[dst[i]], 1);
}

__global__ void blksum_kernel(const int* __restrict__ deg, int* __restrict__ blk, int n) {
    __shared__ int red[256];
    int t = threadIdx.x;
    int base = blockIdx.x * 1024 + t * 4;
    int s = 0;
#pragma unroll
    for (int i = 0; i < 4; ++i) {
        int idx = base + i;
        if (idx < n) s += deg[idx];
    }
    red[t] = s;
    __syncthreads();
    for (int off = 128; off > 0; off >>= 1) {
        if (t < off) red[t] += red[t + off];
        __syncthreads();
    }
    if (t == 0) blk[blockIdx.x] = red[0];
}

__global__ void blkscan_kernel(int* __restrict__ blk, int nb, int* __restrict__ row_ptr, int n) {
    __shared__ int sh[256];
    int t = threadIdx.x;
    int v = (t < nb) ? blk[t] : 0;
    sh[t] = v;
    __syncthreads();
    for (int off = 1; off < 256; off <<= 1) {
        int u = (t >= off) ? sh[t - off] : 0;
        __syncthreads();
        sh[t] += u;
        __syncthreads();
    }
    if (t < nb) blk[t] = (t == 0) ? 0 : sh[t - 1];
    if (t == nb - 1) row_ptr[n] = sh[t];
}

__global__ void emit_kernel(const int* __restrict__ deg, const int* __restrict__ blk,
                            int* __restrict__ row_ptr, int n) {
    __shared__ int red[256];
    int t = threadIdx.x;
    int base = blockIdx.x * 1024 + t * 4;
    int d[4];
    int s = 0;
#pragma unroll
    for (int i = 0; i < 4; ++i) {
        int idx = base + i;
        d[i] = (idx < n) ? deg[idx] : 0;
        s += d[i];
    }
    red[t] = s;
    __syncthreads();
    for (int off = 1; off < 256; off <<= 1) {
        int u = (t >= off) ? red[t - off] : 0;
        __syncthreads();
        red[t] += u;
        __syncthreads();
    }
    int run = blk[blockIdx.x] + ((t == 0) ? 0 : red[t - 1]);
#pragma unroll
    for (int i = 0; i < 4; ++i) {
        int idx = base + i;
        if (idx < n) { row_ptr[idx] = run; run += d[i]; }
    }
}

__global__ void dinv_kernel(const int* __restrict__ deg, float* __restrict__ dinv, int n) {
    int i = blockIdx.x * blockDim.x + threadIdx.x;
    if (i < n) {
        int d = deg[i];
        dinv[i] = (d > 0) ? rsqrtf((float)d) : 0.f;
    }
}

__global__ void scatter_kernel(const int* __restrict__ src, const int* __restrict__ dst,
                               const int* __restrict__ row_ptr, int* __restrict__ cursor,
                               const float* __restrict__ dinv,
                               int2* __restrict__ cw, int e) {
    int i = blockIdx.x * blockDim.x + threadIdx.x;
    if (i >= e) return;
    int s = src[i], d = dst[i];
    int pos = row_ptr[d] + atomicAdd(&cursor[d], 1);
    cw[pos] = make_int2(s, __float_as_int(-dinv[s] * dinv[d]));
}

// ---------------- W padding: [K][dins][douts] -> [K][dind][doutd], zero-filled ---------
__global__ void padw_kernel(const float* __restrict__ src, float* __restrict__ dst,
                            int K, int dins, int douts, int dind, int doutd) {
    int i = blockIdx.x * blockDim.x + threadIdx.x;
    int tot = K * dind * doutd;
    if (i >= tot) return;
    int o = i % doutd;
    int r = i / doutd;
    int dd = r % dind;
    int k = r / dind;
    dst[i] = (dd < dins && o < douts) ? src[((size_t)k * dins + dd) * douts + o] : 0.f;
}

// ---------------- Clenshaw prop: fp16 state, fp32 accumulate ----------------
// r = scale*(L @ feat) - (has_sub ? sub : 0) + add ; writes fp16 (outh) or fp32+BN (outf)
__global__ void proph_kernel(const half4* __restrict__ feat, const half4* __restrict__ sub,
                             const half4* __restrict__ add, half4* __restrict__ outh,
                             f4* __restrict__ outf,
                             const int* __restrict__ row_ptr, const int2* __restrict__ cw,
                             int n, int dim4, float scale, int has_sub,
                             int bnrelu, int used,
                             const float* __restrict__ bn_g, const float* __restrict__ bn_b,
                             const float* __restrict__ bn_m, const float* __restrict__ bn_v) {
    int idx = blockIdx.x * blockDim.x + threadIdx.x;
    if (idx >= n * dim4) return;
    int nd = idx / dim4;
    int f = idx - nd * dim4;
    int e0 = row_ptr[nd], e1 = row_ptr[nd + 1];
    f4 a0 = {0.f, 0.f, 0.f, 0.f}, a1 = a0, a2 = a0, a3 = a0;
    int e = e0;
    for (; e + 4 <= e1; e += 4) {
        int2 q0 = cw[e], q1 = cw[e + 1], q2 = cw[e + 2], q3 = cw[e + 3];
        f4 v0 = __builtin_convertvector(feat[(size_t)q0.x * dim4 + f], f4);
        f4 v1 = __builtin_convertvector(feat[(size_t)q1.x * dim4 + f], f4);
        f4 v2 = __builtin_convertvector(feat[(size_t)q2.x * dim4 + f], f4);
        f4 v3 = __builtin_convertvector(feat[(size_t)q3.x * dim4 + f], f4);
        a0 += __int_as_float(q0.y) * v0;
        a1 += __int_as_float(q1.y) * v1;
        a2 += __int_as_float(q2.y) * v2;
        a3 += __int_as_float(q3.y) * v3;
    }
    for (; e < e1; ++e) {
        int2 q = cw[e];
        f4 v = __builtin_convertvector(feat[(size_t)q.x * dim4 + f], f4);
        a0 += __int_as_float(q.y) * v;
    }
    f4 r = ((a0 + a1) + (a2 + a3)) * scale;
    if (has_sub) r -= __builtin_convertvector(sub[idx], f4);
    r += __builtin_convertvector(add[idx], f4);
    if (bnrelu) {
#pragma unroll
        for (int c = 0; c < 4; ++c) {
            int o = f * 4 + c;
            if (o < used) {
                float sc = bn_g[o] * rsqrtf(bn_v[o] + BN_EPS);
                r[c] = fmaxf(fmaf(r[c] - bn_m[o], sc, bn_b[o]), 0.f);
            } else r[c] = 0.f;
        }
    }
    if (outf) {
        outf[idx] = r;
    } else {
        half4 h;
        h.x = (half1)r.x; h.y = (half1)r.y; h.z = (half1)r.z; h.w = (half1)r.w;
        outh[idx] = h;
    }
}

// layer-4 final: fp16 gathers/streams at stride 12 (dim4=3), fp32 out at stride 10
__global__ void propl_kernel(const half4* __restrict__ feat, const half4* __restrict__ sub,
                             const half4* __restrict__ add, float* __restrict__ out,
                             const int* __restrict__ row_ptr, const int2* __restrict__ cw,
                             int n) {
    int idx = blockIdx.x * blockDim.x + threadIdx.x;
    if (idx >= n * 3) return;
    int nd = idx / 3;
    int f = idx - nd * 3;
    int e0 = row_ptr[nd], e1 = row_ptr[nd + 1];
    f4 a0 = {0.f, 0.f, 0.f, 0.f}, a1 = a0, a2 = a0, a3 = a0;
    int e = e0;
    for (; e + 4 <= e1; e += 4) {
        int2 q0 = cw[e], q1 = cw[e + 1], q2 = cw[e + 2], q3 = cw[e + 3];
        a0 += __int_as_float(q0.y) * __builtin_convertvector(feat[(size_t)q0.x * 3 + f], f4);
        a1 += __int_as_float(q1.y) * __builtin_convertvector(feat[(size_t)q1.x * 3 + f], f4);
        a2 += __int_as_float(q2.y) * __builtin_convertvector(feat[(size_t)q2.x * 3 + f], f4);
        a3 += __int_as_float(q3.y) * __builtin_convertvector(feat[(size_t)q3.x * 3 + f], f4);
    }
    for (; e < e1; ++e) {
        int2 q = cw[e];
        a0 += __int_as_float(q.y) * __builtin_convertvector(feat[(size_t)q.x * 3 + f], f4);
    }
    f4 r = (a0 + a1) + (a2 + a3);
    r -= __builtin_convertvector(sub[idx], f4);
    r += __builtin_convertvector(add[idx], f4);
    int o = f * 4;
    float* orow = out + (size_t)nd * 10;
    if (o + 0 < 10) orow[o + 0] = r.x;
    if (o + 1 < 10) orow[o + 1] = r.y;
    if (o + 2 < 10) orow[o + 2] = r.z;
    if (o + 3 < 10) orow[o + 3] = r.w;
}

// ---------------- layer-1 GEMM: block = 16 waves = (8 k) x (2 out-halves) -------------
// wave-uniform k/oh -> W loads scalarize (s_load); each lane = 1 node, 32 outs.
__global__ __launch_bounds__(1024) void gemm_big_kernel(
        const f4* __restrict__ X4, const float* __restrict__ W,
        const f4* __restrict__ bias4, half4* __restrict__ CB, int n) {
    int lane = threadIdx.x & 63;
    int wv = __builtin_amdgcn_readfirstlane((int)(threadIdx.x >> 6));
    int k = wv & 7;
    int oh = wv >> 3;
    int node0 = blockIdx.x * 64 + lane;
    int node = min(node0, n - 1);
    f4 acc[8];
#pragma unroll
    for (int i = 0; i < 8; ++i) {
        f4 z = {0.f, 0.f, 0.f, 0.f};
        acc[i] = (k == 0) ? bias4[oh * 8 + i] : z;
    }
    const f4* Xr = X4 + (size_t)node * 32;                 // X row: 128 floats
    const float* Wk = W + (size_t)k * 128 * 64 + oh * 32;  // W[k][:][oh*32..]
    for (int d4 = 0; d4 < 32; ++d4) {
        f4 xv = Xr[d4];
#pragma unroll
        for (int j = 0; j < 4; ++j) {
            float xs = xv[j];
            const f4* wr = (const f4*)(Wk + (size_t)(d4 * 4 + j) * 64);
#pragma unroll
            for (int i = 0; i < 8; ++i)
                acc[i] += xs * wr[i];
        }
    }
    if (node0 < n) {
        size_t base = ((size_t)k * n + node) * 16 + oh * 8;  // half4 units, row = 64 halfs
#pragma unroll
        for (int i = 0; i < 8; ++i) {
            half4 h;
            h.x = (half1)acc[i].x; h.y = (half1)acc[i].y;
            h.z = (half1)acc[i].z; h.w = (half1)acc[i].w;
            CB[base + i] = h;
        }
    }
}

// ---------------- small-layer GEMM: block = KK waves, wave k, lane = node -------------
// X fp32 stride DIN4*4 ; Wp padded [k][DIN4*4][NACC*4] ; out fp16 stride NACC*4.
template <int KK, int DIN4, int NACC>
__global__ void gemm_smallw_kernel(const float* __restrict__ X, const float* __restrict__ Wp,
                                   const float* __restrict__ bias, int dout,
                                   half4* __restrict__ CB, int n) {
    int lane = threadIdx.x & 63;
    int k = __builtin_amdgcn_readfirstlane((int)(threadIdx.x >> 6));
    int node0 = blockIdx.x * 64 + lane;
    int node = min(node0, n - 1);
    f4 acc[NACC];
#pragma unroll
    for (int i = 0; i < NACC; ++i) {
        f4 v = {0.f, 0.f, 0.f, 0.f};
        if (k == 0 && bias) {
#pragma unroll
            for (int c = 0; c < 4; ++c) {
                int o = i * 4 + c;
                v[c] = (o < dout) ? bias[o] : 0.f;
            }
        }
        acc[i] = v;
    }
    const f4* Xr = (const f4*)(X + (size_t)node * (DIN4 * 4));
    const f4* Wk = (const f4*)(Wp + (size_t)k * (DIN4 * 4) * (NACC * 4));
    for (int d4 = 0; d4 < DIN4; ++d4) {
        f4 xv = Xr[d4];
#pragma unroll
        for (int j = 0; j < 4; ++j) {
            float xs = xv[j];
#pragma unroll
            for (int i = 0; i < NACC; ++i)
                acc[i] += xs * Wk[(d4 * 4 + j) * NACC + i];
        }
    }
    if (node0 < n) {
        size_t base = ((size_t)k * n + node) * NACC;
#pragma unroll
        for (int i = 0; i < NACC; ++i) {
            half4 h;
            h.x = (half1)acc[i].x; h.y = (half1)acc[i].y;
            h.z = (half1)acc[i].z; h.w = (half1)acc[i].w;
            CB[base + i] = h;
        }
    }
}

// ---------------- host driver ----------------

extern "C" void kernel_launch(void* const* d_in, const int* in_sizes, int n_in,
                              void* d_out, int out_size, void* d_ws, size_t ws_size,
                              hipStream_t stream) {
    const float* x  = (const float*)d_in[0];
    const int*   ei = (const int*)d_in[1];
    const float* Wl[4] = {(const float*)d_in[2], (const float*)d_in[4],
                          (const float*)d_in[6], (const float*)d_in[8]};
    const float* bl[4] = {(const float*)d_in[3], (const float*)d_in[5],
                          (const float*)d_in[7], (const float*)d_in[9]};
    const float* bn[3][4];
    for (int l = 0; l < 3; ++l)
        for (int j = 0; j < 4; ++j)
            bn[l][j] = (const float*)d_in[10 + 4 * l + j];

    char* ws = (char*)d_ws;
    size_t off = 0;
    auto alloc = [&](size_t bytes) -> void* {
        void* p = (void*)(ws + off);
        off = (off + bytes + 255) & ~(size_t)255;
        return p;
    };
    int*   deg     = (int*)alloc(NN * 4);
    int*   row_ptr = (int*)alloc((NN + 1) * 4);
    int*   cursor  = (int*)alloc(NN * 4);
    int*   blks    = (int*)alloc(128 * 4);
    float* dinv    = (float*)alloc(NN * 4);
    int2*  cw      = (int2*)alloc((size_t)NE * 8);
    half1* CB1h    = (half1*)alloc((size_t)8 * NN * 64 * 2);   // layer-1 C slices
    half1* CBsh    = (half1*)alloc((size_t)6 * NN * 20 * 2);   // small-layer C slices
    half1* S0      = (half1*)alloc((size_t)NN * 64 * 2);       // Clenshaw b-state
    half1* S1      = (half1*)alloc((size_t)NN * 64 * 2);
    half1* S2      = (half1*)alloc((size_t)NN * 64 * 2);
    float* H1f     = (float*)alloc((size_t)NN * 64 * 4);
    float* H2f     = (float*)alloc((size_t)NN * 20 * 4);
    float* H3f     = (float*)alloc((size_t)NN * 12 * 4);
    float* Wp2     = (float*)alloc((size_t)6 * 64 * 20 * 4);
    float* Wp3     = (float*)alloc((size_t)4 * 20 * 12 * 4);
    float* Wp4     = (float*)alloc((size_t)4 * 12 * 12 * 4);

    const int* srcp = ei;
    const int* dstp = ei + NE;
    const int nscan = divup(NN, 1024);
    const int NB = divup(NN, 64);

    hipMemsetAsync(deg, 0, NN * 4, stream);
    hipMemsetAsync(cursor, 0, NN * 4, stream);
    hist_kernel<<<divup(NE, 256), 256, 0, stream>>>(dstp, deg, NE);
    blksum_kernel<<<nscan, 256, 0, stream>>>(deg, blks, NN);
    blkscan_kernel<<<1, 256, 0, stream>>>(blks, nscan, row_ptr, NN);
    emit_kernel<<<nscan, 256, 0, stream>>>(deg, blks, row_ptr, NN);
    dinv_kernel<<<divup(NN, 256), 256, 0, stream>>>(deg, dinv, NN);
    scatter_kernel<<<divup(NE, 256), 256, 0, stream>>>(srcp, dstp, row_ptr, cursor, dinv, cw, NE);

    padw_kernel<<<divup(6 * 64 * 20, 256), 256, 0, stream>>>(Wl[1], Wp2, 6, 64, 18, 64, 20);
    padw_kernel<<<divup(4 * 20 * 12, 256), 256, 0, stream>>>(Wl[2], Wp3, 4, 18, 9, 20, 12);
    padw_kernel<<<divup(4 * 12 * 12, 256), 256, 0, stream>>>(Wl[3], Wp4, 4, 9, 10, 12, 12);

    auto prop = [&](const half1* feat, const half1* sub, const half1* add,
                    half1* outh, float* outf, int dim4, float scale,
                    int bnrelu, int used, const float* g, const float* bb,
                    const float* m, const float* v) {
        proph_kernel<<<divup(NN * dim4, 256), 256, 0, stream>>>(
            (const half4*)feat, (const half4*)sub, (const half4*)add,
            (half4*)outh, (f4*)outf, row_ptr, cw, NN, dim4, scale,
            sub != nullptr, bnrelu, used, g, bb, m, v);
    };

    // ---- layer 1 (din=128, dout=64, K=8) -> H1f ----
    gemm_big_kernel<<<NB, 1024, 0, stream>>>((const f4*)x, Wl[0], (const f4*)bl[0],
                                             (half4*)CB1h, NN);
    {
        auto C = [&](int k) { return (const half1*)(CB1h + (size_t)k * NN * 64); };
        prop(C(7), nullptr, C(6), S0, nullptr, 16, 2.f, 0, 64, 0, 0, 0, 0);
        prop(S0, C(7), C(5), S1, nullptr, 16, 2.f, 0, 64, 0, 0, 0, 0);
        prop(S1, S0, C(4), S2, nullptr, 16, 2.f, 0, 64, 0, 0, 0, 0);
        prop(S2, S1, C(3), S0, nullptr, 16, 2.f, 0, 64, 0, 0, 0, 0);
        prop(S0, S2, C(2), S1, nullptr, 16, 2.f, 0, 64, 0, 0, 0, 0);
        prop(S1, S0, C(1), S2, nullptr, 16, 2.f, 0, 64, 0, 0, 0, 0);
        prop(S2, S1, C(0), nullptr, H1f, 16, 1.f, 1, 64,
             bn[0][0], bn[0][1], bn[0][2], bn[0][3]);
    }

    // ---- layer 2 (din=64, dout=18 pad 20, K=6): X=H1f -> H2f ----
    gemm_smallw_kernel<6, 16, 5><<<NB, 384, 0, stream>>>(H1f, Wp2, bl[1], 18,
                                                         (half4*)CBsh, NN);
    {
        auto C = [&](int k) { return (const half1*)(CBsh + (size_t)k * NN * 20); };
        prop(C(5), nullptr, C(4), S0, nullptr, 5, 2.f, 0, 18, 0, 0, 0, 0);
        prop(S0, C(5), C(3), S1, nullptr, 5, 2.f, 0, 18, 0, 0, 0, 0);
        prop(S1, S0, C(2), S2, nullptr, 5, 2.f, 0, 18, 0, 0, 0, 0);
        prop(S2, S1, C(1), S0, nullptr, 5, 2.f, 0, 18, 0, 0, 0, 0);
        prop(S0, S2, C(0), nullptr, H2f, 5, 1.f, 1, 18,
             bn[1][0], bn[1][1], bn[1][2], bn[1][3]);
    }

    // ---- layer 3 (din=18 str20, dout=9 pad 12, K=4): X=H2f -> H3f ----
    gemm_smallw_kernel<4, 5, 3><<<NB, 256, 0, stream>>>(H2f, Wp3, bl[2], 9,
                                                        (half4*)CBsh, NN);
    {
        auto C = [&](int k) { return (const half1*)(CBsh + (size_t)k * NN * 12); };
        prop(C(3), nullptr, C(2), S0, nullptr, 3, 2.f, 0, 9, 0, 0, 0, 0);
        prop(S0, C(3), C(1), S1, nullptr, 3, 2.f, 0, 9, 0, 0, 0, 0);
        prop(S1, S0, C(0), nullptr, H3f, 3, 1.f, 1, 9,
             bn[2][0], bn[2][1], bn[2][2], bn[2][3]);
    }

    // ---- layer 4 (din=9 str12, dout=10 pad 12, K=4): X=H3f -> d_out ----
    gemm_smallw_kernel<4, 3, 3><<<NB, 256, 0, stream>>>(H3f, Wp4, bl[3], 10,
                                                        (half4*)CBsh, NN);
    {
        auto C = [&](int k) { return (const half1*)(CBsh + (size_t)k * NN * 12); };
        prop(C(3), nullptr, C(2), S0, nullptr, 3, 2.f, 0, 10, 0, 0, 0, 0);
        prop(S0, C(3), C(1), S1, nullptr, 3, 2.f, 0, 10, 0, 0, 0, 0);
        propl_kernel<<<divup(NN * 3, 256), 256, 0, stream>>>(
            (const half4*)S1, (const half4*)S0, (const half4*)CBsh,
            (float*)d_out, row_ptr, cw, NN);
    }
}

// Round 8
// 970.979 us; speedup vs baseline: 5.4370x; 1.0537x over previous
//
#include <hip/hip_runtime.h>

#define NN 100000
#define NE 1600000
#define BN_EPS 1e-5f

typedef _Float16 half1;
typedef _Float16 half4 __attribute__((ext_vector_type(4)));
typedef _Float16 h8 __attribute__((ext_vector_type(8)));
typedef float f4 __attribute__((ext_vector_type(4)));

static inline int divup(int a, int b) { return (a + b - 1) / b; }

// ---------------- preprocessing ----------------

__global__ void hist_kernel(const int* __restrict__ dst, int* __restrict__ deg, int e) {
    int i = blockIdx.x * blockDim.x + threadIdx.x;
    if (i < e) atomicAdd(&deg[dst[i]], 1);
}

__global__ void blksum_kernel(const int* __restrict__ deg, int* __restrict__ blk, int n) {
    __shared__ int red[256];
    int t = threadIdx.x;
    int base = blockIdx.x * 1024 + t * 4;
    int s = 0;
#pragma unroll
    for (int i = 0; i < 4; ++i) {
        int idx = base + i;
        if (idx < n) s += deg[idx];
    }
    red[t] = s;
    __syncthreads();
    for (int off = 128; off > 0; off >>= 1) {
        if (t < off) red[t] += red[t + off];
        __syncthreads();
    }
    if (t == 0) blk[blockIdx.x] = red[0];
}

__global__ void blkscan_kernel(int* __restrict__ blk, int nb, int* __restrict__ row_ptr, int n) {
    __shared__ int sh[256];
    int t = threadIdx.x;
    int v = (t < nb) ? blk[t] : 0;
    sh[t] = v;
    __syncthreads();
    for (int off = 1; off < 256; off <<= 1) {
        int u = (t >= off) ? sh[t - off] : 0;
        __syncthreads();
        sh[t] += u;
        __syncthreads();
    }
    if (t < nb) blk[t] = (t == 0) ? 0 : sh[t - 1];
    if (t == nb - 1) row_ptr[n] = sh[t];
}

__global__ void emit_kernel(const int* __restrict__ deg, const int* __restrict__ blk,
                            int* __restrict__ row_ptr, int n) {
    __shared__ int red[256];
    int t = threadIdx.x;
    int base = blockIdx.x * 1024 + t * 4;
    int d[4];
    int s = 0;
#pragma unroll
    for (int i = 0; i < 4; ++i) {
        int idx = base + i;
        d[i] = (idx < n) ? deg[idx] : 0;
        s += d[i];
    }
    red[t] = s;
    __syncthreads();
    for (int off = 1; off < 256; off <<= 1) {
        int u = (t >= off) ? red[t - off] : 0;
        __syncthreads();
        red[t] += u;
        __syncthreads();
    }
    int run = blk[blockIdx.x] + ((t == 0) ? 0 : red[t - 1]);
#pragma unroll
    for (int i = 0; i < 4; ++i) {
        int idx = base + i;
        if (idx < n) { row_ptr[idx] = run; run += d[i]; }
    }
}

__global__ void dinv_kernel(const int* __restrict__ deg, float* __restrict__ dinv, int n) {
    int i = blockIdx.x * blockDim.x + threadIdx.x;
    if (i < n) {
        int d = deg[i];
        dinv[i] = (d > 0) ? rsqrtf((float)d) : 0.f;
    }
}

__global__ void scatter_kernel(const int* __restrict__ src, const int* __restrict__ dst,
                               const int* __restrict__ row_ptr, int* __restrict__ cursor,
                               const float* __restrict__ dinv,
                               int2* __restrict__ cw, int e) {
    int i = blockIdx.x * blockDim.x + threadIdx.x;
    if (i >= e) return;
    int s = src[i], d = dst[i];
    int pos = row_ptr[d] + atomicAdd(&cursor[d], 1);
    cw[pos] = make_int2(s, __float_as_int(-dinv[s] * dinv[d]));
}

// ---------------- fp16 converts for MFMA ----------------

__global__ void cvtx_kernel(const float4* __restrict__ X, half4* __restrict__ Xh, int tot4) {
    int i = blockIdx.x * blockDim.x + threadIdx.x;
    if (i >= tot4) return;
    float4 v = X[i];
    half4 h;
    h.x = (half1)v.x; h.y = (half1)v.y; h.z = (half1)v.z; h.w = (half1)v.w;
    Xh[i] = h;
}

// Wt[og][kd] = W1[og>>6][kd][og&63], fp16 ; Wt is [512][128]
__global__ void transw_kernel(const float* __restrict__ W, half1* __restrict__ Wt) {
    int i = blockIdx.x * blockDim.x + threadIdx.x;
    if (i >= 512 * 128) return;
    int kd = i >> 9;
    int og = i & 511;
    int k = og >> 6, o = og & 63;
    Wt[(size_t)og * 128 + kd] = (half1)W[((size_t)k * 128 + kd) * 64 + o];
}

// ---------------- W padding: [K][dins][douts] -> [K][dind][doutd], zero-filled ---------
__global__ void padw_kernel(const float* __restrict__ src, float* __restrict__ dst,
                            int K, int dins, int douts, int dind, int doutd) {
    int i = blockIdx.x * blockDim.x + threadIdx.x;
    int tot = K * dind * doutd;
    if (i >= tot) return;
    int o = i % doutd;
    int r = i / doutd;
    int dd = r % dind;
    int k = r / dind;
    dst[i] = (dd < dins && o < douts) ? src[((size_t)k * dins + dd) * douts + o] : 0.f;
}

// ---------------- Clenshaw prop: fp16 state, fp32 accumulate ----------------
__global__ void proph_kernel(const half4* __restrict__ feat, const half4* __restrict__ sub,
                             const half4* __restrict__ add, half4* __restrict__ outh,
                             f4* __restrict__ outf,
                             const int* __restrict__ row_ptr, const int2* __restrict__ cw,
                             int n, int dim4, float scale, int has_sub,
                             int bnrelu, int used,
                             const float* __restrict__ bn_g, const float* __restrict__ bn_b,
                             const float* __restrict__ bn_m, const float* __restrict__ bn_v) {
    int idx = blockIdx.x * blockDim.x + threadIdx.x;
    if (idx >= n * dim4) return;
    int nd = idx / dim4;
    int f = idx - nd * dim4;
    int e0 = row_ptr[nd], e1 = row_ptr[nd + 1];
    f4 a0 = {0.f, 0.f, 0.f, 0.f}, a1 = a0, a2 = a0, a3 = a0;
    int e = e0;
    for (; e + 4 <= e1; e += 4) {
        int2 q0 = cw[e], q1 = cw[e + 1], q2 = cw[e + 2], q3 = cw[e + 3];
        f4 v0 = __builtin_convertvector(feat[(size_t)q0.x * dim4 + f], f4);
        f4 v1 = __builtin_convertvector(feat[(size_t)q1.x * dim4 + f], f4);
        f4 v2 = __builtin_convertvector(feat[(size_t)q2.x * dim4 + f], f4);
        f4 v3 = __builtin_convertvector(feat[(size_t)q3.x * dim4 + f], f4);
        a0 += __int_as_float(q0.y) * v0;
        a1 += __int_as_float(q1.y) * v1;
        a2 += __int_as_float(q2.y) * v2;
        a3 += __int_as_float(q3.y) * v3;
    }
    for (; e < e1; ++e) {
        int2 q = cw[e];
        f4 v = __builtin_convertvector(feat[(size_t)q.x * dim4 + f], f4);
        a0 += __int_as_float(q.y) * v;
    }
    f4 r = ((a0 + a1) + (a2 + a3)) * scale;
    if (has_sub) r -= __builtin_convertvector(sub[idx], f4);
    r += __builtin_convertvector(add[idx], f4);
    if (bnrelu) {
#pragma unroll
        for (int c = 0; c < 4; ++c) {
            int o = f * 4 + c;
            if (o < used) {
                float sc = bn_g[o] * rsqrtf(bn_v[o] + BN_EPS);
                r[c] = fmaxf(fmaf(r[c] - bn_m[o], sc, bn_b[o]), 0.f);
            } else r[c] = 0.f;
        }
    }
    if (outf) {
        outf[idx] = r;
    } else {
        half4 h;
        h.x = (half1)r.x; h.y = (half1)r.y; h.z = (half1)r.z; h.w = (half1)r.w;
        outh[idx] = h;
    }
}

// layer-4 final: fp16 gathers/streams at stride 12 (dim4=3), fp32 out at stride 10
__global__ void propl_kernel(const half4* __restrict__ feat, const half4* __restrict__ sub,
                             const half4* __restrict__ add, float* __restrict__ out,
                             const int* __restrict__ row_ptr, const int2* __restrict__ cw,
                             int n) {
    int idx = blockIdx.x * blockDim.x + threadIdx.x;
    if (idx >= n * 3) return;
    int nd = idx / 3;
    int f = idx - nd * 3;
    int e0 = row_ptr[nd], e1 = row_ptr[nd + 1];
    f4 a0 = {0.f, 0.f, 0.f, 0.f}, a1 = a0, a2 = a0, a3 = a0;
    int e = e0;
    for (; e + 4 <= e1; e += 4) {
        int2 q0 = cw[e], q1 = cw[e + 1], q2 = cw[e + 2], q3 = cw[e + 3];
        a0 += __int_as_float(q0.y) * __builtin_convertvector(feat[(size_t)q0.x * 3 + f], f4);
        a1 += __int_as_float(q1.y) * __builtin_convertvector(feat[(size_t)q1.x * 3 + f], f4);
        a2 += __int_as_float(q2.y) * __builtin_convertvector(feat[(size_t)q2.x * 3 + f], f4);
        a3 += __int_as_float(q3.y) * __builtin_convertvector(feat[(size_t)q3.x * 3 + f], f4);
    }
    for (; e < e1; ++e) {
        int2 q = cw[e];
        a0 += __int_as_float(q.y) * __builtin_convertvector(feat[(size_t)q.x * 3 + f], f4);
    }
    f4 r = (a0 + a1) + (a2 + a3);
    r -= __builtin_convertvector(sub[idx], f4);
    r += __builtin_convertvector(add[idx], f4);
    int o = f * 4;
    float* orow = out + (size_t)nd * 10;
    if (o + 0 < 10) orow[o + 0] = r.x;
    if (o + 1 < 10) orow[o + 1] = r.y;
    if (o + 2 < 10) orow[o + 2] = r.z;
    if (o + 3 < 10) orow[o + 3] = r.w;
}

// ---------------- layer-1 GEMM via MFMA ----------------
// M=n, N=512 (8 k-slices x 64 outs), K=128. fp16 in, fp32 acc, fp16 out to CB slices.
// Wave computes 16 nodes x 64 outs: 4 kc-chunks x 4 out-subtiles of mfma_f32_16x16x32_f16.
// A-frag: m=lane&15, k=quad*8+j (16B contiguous). B-frag symmetric from Wt[og][128].
// C/D: col(=out)=lane&15, row(=node)=quad*4+reg  [HW-verified layouts].
__global__ __launch_bounds__(256) void gemm_mfma_kernel(
        const half1* __restrict__ Xh, const half1* __restrict__ Wt,
        const float* __restrict__ bias, half1* __restrict__ CB, int n) {
    int lane = threadIdx.x & 63;
    int wave = threadIdx.x >> 6;
    int m16 = lane & 15;
    int quad = lane >> 4;
    int ntile = blockIdx.x * 16;
    int obase = blockIdx.y * 256 + wave * 64;
    int nodeA = min(ntile + m16, n - 1);
    const h8* Arow = (const h8*)(Xh + (size_t)nodeA * 128);   // 16 h8 chunks/row
    f4 acc[4];
#pragma unroll
    for (int i = 0; i < 4; ++i) acc[i] = (f4){0.f, 0.f, 0.f, 0.f};
#pragma unroll
    for (int kc = 0; kc < 4; ++kc) {
        h8 a = Arow[kc * 4 + quad];
#pragma unroll
        for (int i = 0; i < 4; ++i) {
            const h8* Brow = (const h8*)(Wt + (size_t)(obase + i * 16 + m16) * 128);
            h8 b = Brow[kc * 4 + quad];
            acc[i] = __builtin_amdgcn_mfma_f32_16x16x32_f16(a, b, acc[i], 0, 0, 0);
        }
    }
#pragma unroll
    for (int i = 0; i < 4; ++i) {
        int og = obase + i * 16 + m16;
        int ks = og >> 6, o = og & 63;
#pragma unroll
        for (int reg = 0; reg < 4; ++reg) {
            int node = ntile + quad * 4 + reg;
            if (node < n) {
                float v = acc[i][reg];
                if (ks == 0) v += bias[o];
                CB[((size_t)ks * n + node) * 64 + o] = (half1)v;
            }
        }
    }
}

// ---------------- small-layer GEMM: block = KK waves, wave k, lane = node -------------
template <int KK, int DIN4, int NACC>
__global__ void gemm_smallw_kernel(const float* __restrict__ X, const float* __restrict__ Wp,
                                   const float* __restrict__ bias, int dout,
                                   half4* __restrict__ CB, int n) {
    int lane = threadIdx.x & 63;
    int k = __builtin_amdgcn_readfirstlane((int)(threadIdx.x >> 6));
    int node0 = blockIdx.x * 64 + lane;
    int node = min(node0, n - 1);
    f4 acc[NACC];
#pragma unroll
    for (int i = 0; i < NACC; ++i) {
        f4 v = {0.f, 0.f, 0.f, 0.f};
        if (k == 0 && bias) {
#pragma unroll
            for (int c = 0; c < 4; ++c) {
                int o = i * 4 + c;
                v[c] = (o < dout) ? bias[o] : 0.f;
            }
        }
        acc[i] = v;
    }
    const f4* Xr = (const f4*)(X + (size_t)node * (DIN4 * 4));
    const f4* Wk = (const f4*)(Wp + (size_t)k * (DIN4 * 4) * (NACC * 4));
    for (int d4 = 0; d4 < DIN4; ++d4) {
        f4 xv = Xr[d4];
#pragma unroll
        for (int j = 0; j < 4; ++j) {
            float xs = xv[j];
#pragma unroll
            for (int i = 0; i < NACC; ++i)
                acc[i] += xs * Wk[(d4 * 4 + j) * NACC + i];
        }
    }
    if (node0 < n) {
        size_t base = ((size_t)k * n + node) * NACC;
#pragma unroll
        for (int i = 0; i < NACC; ++i) {
            half4 h;
            h.x = (half1)acc[i].x; h.y = (half1)acc[i].y;
            h.z = (half1)acc[i].z; h.w = (half1)acc[i].w;
            CB[base + i] = h;
        }
    }
}

// ---------------- host driver ----------------

extern "C" void kernel_launch(void* const* d_in, const int* in_sizes, int n_in,
                              void* d_out, int out_size, void* d_ws, size_t ws_size,
                              hipStream_t stream) {
    const float* x  = (const float*)d_in[0];
    const int*   ei = (const int*)d_in[1];
    const float* Wl[4] = {(const float*)d_in[2], (const float*)d_in[4],
                          (const float*)d_in[6], (const float*)d_in[8]};
    const float* bl[4] = {(const float*)d_in[3], (const float*)d_in[5],
                          (const float*)d_in[7], (const float*)d_in[9]};
    const float* bn[3][4];
    for (int l = 0; l < 3; ++l)
        for (int j = 0; j < 4; ++j)
            bn[l][j] = (const float*)d_in[10 + 4 * l + j];

    char* ws = (char*)d_ws;
    size_t off = 0;
    auto alloc = [&](size_t bytes) -> void* {
        void* p = (void*)(ws + off);
        off = (off + bytes + 255) & ~(size_t)255;
        return p;
    };
    int*   deg     = (int*)alloc(NN * 4);
    int*   row_ptr = (int*)alloc((NN + 1) * 4);
    int*   cursor  = (int*)alloc(NN * 4);
    int*   blks    = (int*)alloc(128 * 4);
    float* dinv    = (float*)alloc(NN * 4);
    int2*  cw      = (int2*)alloc((size_t)NE * 8);
    half1* CB1h    = (half1*)alloc((size_t)8 * NN * 64 * 2);
    half1* CBsh    = (half1*)alloc((size_t)6 * NN * 20 * 2);
    half1* S0      = (half1*)alloc((size_t)NN * 64 * 2);
    half1* S1      = (half1*)alloc((size_t)NN * 64 * 2);
    half1* S2      = (half1*)alloc((size_t)NN * 64 * 2);
    float* H1f     = (float*)alloc((size_t)NN * 64 * 4);
    float* H2f     = (float*)alloc((size_t)NN * 20 * 4);
    float* H3f     = (float*)alloc((size_t)NN * 12 * 4);
    float* Wp2     = (float*)alloc((size_t)6 * 64 * 20 * 4);
    float* Wp3     = (float*)alloc((size_t)4 * 20 * 12 * 4);
    float* Wp4     = (float*)alloc((size_t)4 * 12 * 12 * 4);
    half1* Xh      = (half1*)alloc((size_t)NN * 128 * 2);
    half1* Wt1     = (half1*)alloc((size_t)512 * 128 * 2);

    const int* srcp = ei;
    const int* dstp = ei + NE;
    const int nscan = divup(NN, 1024);
    const int NB = divup(NN, 64);

    hipMemsetAsync(deg, 0, NN * 4, stream);
    hipMemsetAsync(cursor, 0, NN * 4, stream);
    hist_kernel<<<divup(NE, 256), 256, 0, stream>>>(dstp, deg, NE);
    blksum_kernel<<<nscan, 256, 0, stream>>>(deg, blks, NN);
    blkscan_kernel<<<1, 256, 0, stream>>>(blks, nscan, row_ptr, NN);
    emit_kernel<<<nscan, 256, 0, stream>>>(deg, blks, row_ptr, NN);
    dinv_kernel<<<divup(NN, 256), 256, 0, stream>>>(deg, dinv, NN);
    scatter_kernel<<<divup(NE, 256), 256, 0, stream>>>(srcp, dstp, row_ptr, cursor, dinv, cw, NE);

    cvtx_kernel<<<divup(NN * 32, 256), 256, 0, stream>>>((const float4*)x, (half4*)Xh, NN * 32);
    transw_kernel<<<divup(512 * 128, 256), 256, 0, stream>>>(Wl[0], Wt1);
    padw_kernel<<<divup(6 * 64 * 20, 256), 256, 0, stream>>>(Wl[1], Wp2, 6, 64, 18, 64, 20);
    padw_kernel<<<divup(4 * 20 * 12, 256), 256, 0, stream>>>(Wl[2], Wp3, 4, 18, 9, 20, 12);
    padw_kernel<<<divup(4 * 12 * 12, 256), 256, 0, stream>>>(Wl[3], Wp4, 4, 9, 10, 12, 12);

    auto prop = [&](const half1* feat, const half1* sub, const half1* add,
                    half1* outh, float* outf, int dim4, float scale,
                    int bnrelu, int used, const float* g, const float* bb,
                    const float* m, const float* v) {
        proph_kernel<<<divup(NN * dim4, 256), 256, 0, stream>>>(
            (const half4*)feat, (const half4*)sub, (const half4*)add,
            (half4*)outh, (f4*)outf, row_ptr, cw, NN, dim4, scale,
            sub != nullptr, bnrelu, used, g, bb, m, v);
    };

    // ---- layer 1 (din=128, dout=64, K=8) -> H1f ----
    gemm_mfma_kernel<<<dim3(divup(NN, 16), 2), 256, 0, stream>>>(Xh, Wt1, bl[0], CB1h, NN);
    {
        auto C = [&](int k) { return (const half1*)(CB1h + (size_t)k * NN * 64); };
        prop(C(7), nullptr, C(6), S0, nullptr, 16, 2.f, 0, 64, 0, 0, 0, 0);
        prop(S0, C(7), C(5), S1, nullptr, 16, 2.f, 0, 64, 0, 0, 0, 0);
        prop(S1, S0, C(4), S2, nullptr, 16, 2.f, 0, 64, 0, 0, 0, 0);
        prop(S2, S1, C(3), S0, nullptr, 16, 2.f, 0, 64, 0, 0, 0, 0);
        prop(S0, S2, C(2), S1, nullptr, 16, 2.f, 0, 64, 0, 0, 0, 0);
        prop(S1, S0, C(1), S2, nullptr, 16, 2.f, 0, 64, 0, 0, 0, 0);
        prop(S2, S1, C(0), nullptr, H1f, 16, 1.f, 1, 64,
             bn[0][0], bn[0][1], bn[0][2], bn[0][3]);
    }

    // ---- layer 2 (din=64, dout=18 pad 20, K=6): X=H1f -> H2f ----
    gemm_smallw_kernel<6, 16, 5><<<NB, 384, 0, stream>>>(H1f, Wp2, bl[1], 18,
                                                         (half4*)CBsh, NN);
    {
        auto C = [&](int k) { return (const half1*)(CBsh + (size_t)k * NN * 20); };
        prop(C(5), nullptr, C(4), S0, nullptr, 5, 2.f, 0, 18, 0, 0, 0, 0);
        prop(S0, C(5), C(3), S1, nullptr, 5, 2.f, 0, 18, 0, 0, 0, 0);
        prop(S1, S0, C(2), S2, nullptr, 5, 2.f, 0, 18, 0, 0, 0, 0);
        prop(S2, S1, C(1), S0, nullptr, 5, 2.f, 0, 18, 0, 0, 0, 0);
        prop(S0, S2, C(0), nullptr, H2f, 5, 1.f, 1, 18,
             bn[1][0], bn[1][1], bn[1][2], bn[1][3]);
    }

    // ---- layer 3 (din=18 str20, dout=9 pad 12, K=4): X=H2f -> H3f ----
    gemm_smallw_kernel<4, 5, 3><<<NB, 256, 0, stream>>>(H2f, Wp3, bl[2], 9,
                                                        (half4*)CBsh, NN);
    {
        auto C = [&](int k) { return (const half1*)(CBsh + (size_t)k * NN * 12); };
        prop(C(3), nullptr, C(2), S0, nullptr, 3, 2.f, 0, 9, 0, 0, 0, 0);
        prop(S0, C(3), C(1), S1, nullptr, 3, 2.f, 0, 9, 0, 0, 0, 0);
        prop(S1, S0, C(0), nullptr, H3f, 3, 1.f, 1, 9,
             bn[2][0], bn[2][1], bn[2][2], bn[2][3]);
    }

    // ---- layer 4 (din=9 str12, dout=10 pad 12, K=4): X=H3f -> d_out ----
    gemm_smallw_kernel<4, 3, 3><<<NB, 256, 0, stream>>>(H3f, Wp4, bl[3], 10,
                                                        (half4*)CBsh, NN);
    {
        auto C = [&](int k) { return (const half1*)(CBsh + (size_t)k * NN * 12); };
        prop(C(3), nullptr, C(2), S0, nullptr, 3, 2.f, 0, 10, 0, 0, 0, 0);
        prop(S0, C(3), C(1), S1, nullptr, 3, 2.f, 0, 10, 0, 0, 0, 0);
        propl_kernel<<<divup(NN * 3, 256), 256, 0, stream>>>(
            (const half4*)S1, (const half4*)S0, (const half4*)CBsh,
            (float*)d_out, row_ptr, cw, NN);
    }
}

// Round 9
// 914.493 us; speedup vs baseline: 5.7728x; 1.0618x over previous
//
#include <hip/hip_runtime.h>

#define NN 100000
#define NE 1600000
#define BN_EPS 1e-5f

typedef _Float16 half1;
typedef _Float16 half4 __attribute__((ext_vector_type(4)));
typedef _Float16 h8 __attribute__((ext_vector_type(8)));
typedef float f4 __attribute__((ext_vector_type(4)));

static inline int divup(int a, int b) { return (a + b - 1) / b; }

// ---------------- preprocessing ----------------

__global__ void hist_kernel(const int* __restrict__ dst, int* __restrict__ deg, int e) {
    int i = blockIdx.x * blockDim.x + threadIdx.x;
    if (i < e) atomicAdd(&deg[dst[i]], 1);
}

__global__ void blksum_kernel(const int* __restrict__ deg, int* __restrict__ blk, int n) {
    __shared__ int red[256];
    int t = threadIdx.x;
    int base = blockIdx.x * 1024 + t * 4;
    int s = 0;
#pragma unroll
    for (int i = 0; i < 4; ++i) {
        int idx = base + i;
        if (idx < n) s += deg[idx];
    }
    red[t] = s;
    __syncthreads();
    for (int off = 128; off > 0; off >>= 1) {
        if (t < off) red[t] += red[t + off];
        __syncthreads();
    }
    if (t == 0) blk[blockIdx.x] = red[0];
}

__global__ void blkscan_kernel(int* __restrict__ blk, int nb, int* __restrict__ row_ptr, int n) {
    __shared__ int sh[256];
    int t = threadIdx.x;
    int v = (t < nb) ? blk[t] : 0;
    sh[t] = v;
    __syncthreads();
    for (int off = 1; off < 256; off <<= 1) {
        int u = (t >= off) ? sh[t - off] : 0;
        __syncthreads();
        sh[t] += u;
        __syncthreads();
    }
    if (t < nb) blk[t] = (t == 0) ? 0 : sh[t - 1];
    if (t == nb - 1) row_ptr[n] = sh[t];
}

__global__ void emit_kernel(const int* __restrict__ deg, const int* __restrict__ blk,
                            int* __restrict__ row_ptr, int n) {
    __shared__ int red[256];
    int t = threadIdx.x;
    int base = blockIdx.x * 1024 + t * 4;
    int d[4];
    int s = 0;
#pragma unroll
    for (int i = 0; i < 4; ++i) {
        int idx = base + i;
        d[i] = (idx < n) ? deg[idx] : 0;
        s += d[i];
    }
    red[t] = s;
    __syncthreads();
    for (int off = 1; off < 256; off <<= 1) {
        int u = (t >= off) ? red[t - off] : 0;
        __syncthreads();
        red[t] += u;
        __syncthreads();
    }
    int run = blk[blockIdx.x] + ((t == 0) ? 0 : red[t - 1]);
#pragma unroll
    for (int i = 0; i < 4; ++i) {
        int idx = base + i;
        if (idx < n) { row_ptr[idx] = run; run += d[i]; }
    }
}

__global__ void dinv_kernel(const int* __restrict__ deg, float* __restrict__ dinv, int n) {
    int i = blockIdx.x * blockDim.x + threadIdx.x;
    if (i < n) {
        int d = deg[i];
        dinv[i] = (d > 0) ? rsqrtf((float)d) : 0.f;
    }
}

__global__ void scatter_kernel(const int* __restrict__ src, const int* __restrict__ dst,
                               const int* __restrict__ row_ptr, int* __restrict__ cursor,
                               const float* __restrict__ dinv,
                               int2* __restrict__ cw, int e) {
    int i = blockIdx.x * blockDim.x + threadIdx.x;
    if (i >= e) return;
    int s = src[i], d = dst[i];
    int pos = row_ptr[d] + atomicAdd(&cursor[d], 1);
    cw[pos] = make_int2(s, __float_as_int(-dinv[s] * dinv[d]));
}

// ---------------- fp16 converts for MFMA ----------------

__global__ void cvtx_kernel(const float4* __restrict__ X, half4* __restrict__ Xh, int tot4) {
    int i = blockIdx.x * blockDim.x + threadIdx.x;
    if (i >= tot4) return;
    float4 v = X[i];
    half4 h;
    h.x = (half1)v.x; h.y = (half1)v.y; h.z = (half1)v.z; h.w = (half1)v.w;
    Xh[i] = h;
}

// Wt[og][kd] = W1[og>>6][kd][og&63], fp16 ; Wt is [512][128]
__global__ void transw_kernel(const float* __restrict__ W, half1* __restrict__ Wt) {
    int i = blockIdx.x * blockDim.x + threadIdx.x;
    if (i >= 512 * 128) return;
    int kd = i >> 9;
    int og = i & 511;
    int k = og >> 6, o = og & 63;
    Wt[(size_t)og * 128 + kd] = (half1)W[((size_t)k * 128 + kd) * 64 + o];
}

// ---------------- W padding: [K][dins][douts] -> [K][dind][doutd], zero-filled ---------
__global__ void padw_kernel(const float* __restrict__ src, float* __restrict__ dst,
                            int K, int dins, int douts, int dind, int doutd) {
    int i = blockIdx.x * blockDim.x + threadIdx.x;
    int tot = K * dind * doutd;
    if (i >= tot) return;
    int o = i % doutd;
    int r = i / doutd;
    int dd = r % dind;
    int k = r / dind;
    dst[i] = (dd < dins && o < douts) ? src[((size_t)k * dins + dd) * douts + o] : 0.f;
}

// ---------------- Clenshaw prop: fp16 state, fp32 accumulate ----------------
__global__ void proph_kernel(const half4* __restrict__ feat, const half4* __restrict__ sub,
                             const half4* __restrict__ add, half4* __restrict__ outh,
                             f4* __restrict__ outf,
                             const int* __restrict__ row_ptr, const int2* __restrict__ cw,
                             int n, int dim4, float scale, int has_sub,
                             int bnrelu, int used,
                             const float* __restrict__ bn_g, const float* __restrict__ bn_b,
                             const float* __restrict__ bn_m, const float* __restrict__ bn_v) {
    int idx = blockIdx.x * blockDim.x + threadIdx.x;
    if (idx >= n * dim4) return;
    int nd = idx / dim4;
    int f = idx - nd * dim4;
    int e0 = row_ptr[nd], e1 = row_ptr[nd + 1];
    f4 a0 = {0.f, 0.f, 0.f, 0.f}, a1 = a0, a2 = a0, a3 = a0;
    int e = e0;
    for (; e + 4 <= e1; e += 4) {
        int2 q0 = cw[e], q1 = cw[e + 1], q2 = cw[e + 2], q3 = cw[e + 3];
        f4 v0 = __builtin_convertvector(feat[(size_t)q0.x * dim4 + f], f4);
        f4 v1 = __builtin_convertvector(feat[(size_t)q1.x * dim4 + f], f4);
        f4 v2 = __builtin_convertvector(feat[(size_t)q2.x * dim4 + f], f4);
        f4 v3 = __builtin_convertvector(feat[(size_t)q3.x * dim4 + f], f4);
        a0 += __int_as_float(q0.y) * v0;
        a1 += __int_as_float(q1.y) * v1;
        a2 += __int_as_float(q2.y) * v2;
        a3 += __int_as_float(q3.y) * v3;
    }
    for (; e < e1; ++e) {
        int2 q = cw[e];
        f4 v = __builtin_convertvector(feat[(size_t)q.x * dim4 + f], f4);
        a0 += __int_as_float(q.y) * v;
    }
    f4 r = ((a0 + a1) + (a2 + a3)) * scale;
    if (has_sub) r -= __builtin_convertvector(sub[idx], f4);
    r += __builtin_convertvector(add[idx], f4);
    if (bnrelu) {
#pragma unroll
        for (int c = 0; c < 4; ++c) {
            int o = f * 4 + c;
            if (o < used) {
                float sc = bn_g[o] * rsqrtf(bn_v[o] + BN_EPS);
                r[c] = fmaxf(fmaf(r[c] - bn_m[o], sc, bn_b[o]), 0.f);
            } else r[c] = 0.f;
        }
    }
    if (outf) {
        outf[idx] = r;
    } else {
        half4 h;
        h.x = (half1)r.x; h.y = (half1)r.y; h.z = (half1)r.z; h.w = (half1)r.w;
        outh[idx] = h;
    }
}

// layer-4 final: fp16 gathers/streams at stride 12 (dim4=3), fp32 out at stride 10
__global__ void propl_kernel(const half4* __restrict__ feat, const half4* __restrict__ sub,
                             const half4* __restrict__ add, float* __restrict__ out,
                             const int* __restrict__ row_ptr, const int2* __restrict__ cw,
                             int n) {
    int idx = blockIdx.x * blockDim.x + threadIdx.x;
    if (idx >= n * 3) return;
    int nd = idx / 3;
    int f = idx - nd * 3;
    int e0 = row_ptr[nd], e1 = row_ptr[nd + 1];
    f4 a0 = {0.f, 0.f, 0.f, 0.f}, a1 = a0, a2 = a0, a3 = a0;
    int e = e0;
    for (; e + 4 <= e1; e += 4) {
        int2 q0 = cw[e], q1 = cw[e + 1], q2 = cw[e + 2], q3 = cw[e + 3];
        a0 += __int_as_float(q0.y) * __builtin_convertvector(feat[(size_t)q0.x * 3 + f], f4);
        a1 += __int_as_float(q1.y) * __builtin_convertvector(feat[(size_t)q1.x * 3 + f], f4);
        a2 += __int_as_float(q2.y) * __builtin_convertvector(feat[(size_t)q2.x * 3 + f], f4);
        a3 += __int_as_float(q3.y) * __builtin_convertvector(feat[(size_t)q3.x * 3 + f], f4);
    }
    for (; e < e1; ++e) {
        int2 q = cw[e];
        a0 += __int_as_float(q.y) * __builtin_convertvector(feat[(size_t)q.x * 3 + f], f4);
    }
    f4 r = (a0 + a1) + (a2 + a3);
    r -= __builtin_convertvector(sub[idx], f4);
    r += __builtin_convertvector(add[idx], f4);
    int o = f * 4;
    float* orow = out + (size_t)nd * 10;
    if (o + 0 < 10) orow[o + 0] = r.x;
    if (o + 1 < 10) orow[o + 1] = r.y;
    if (o + 2 < 10) orow[o + 2] = r.z;
    if (o + 3 < 10) orow[o + 3] = r.w;
}

// ---------------- layer-1 GEMM via MFMA (swapped operands) ----------------
// A = Wt (m = out index), B = Xh (n = node). D layout: row=quad*4+reg = out,
// col=lane&15 = node -> each lane packs 4 consecutive outs as half4 (8B stores).
// Wave: 64 nodes x 64 outs (one ks slice) = 4 node-tiles x 4 out-subtiles x 4 kc = 64 MFMA.
// Block: 4 waves = 4 ks slices for the same 64 nodes; blockIdx.y picks ks group.
__global__ __launch_bounds__(256) void gemm_mfma_kernel(
        const half1* __restrict__ Xh, const half1* __restrict__ Wt,
        const float* __restrict__ bias, half1* __restrict__ CB, int n) {
    int lane = threadIdx.x & 63;
    int wave = threadIdx.x >> 6;
    int m16 = lane & 15;
    int quad = lane >> 4;
    int ks = blockIdx.y * 4 + wave;
    int ntile = blockIdx.x * 64;

    f4 acc[4][4];   // [node-tile][out-subtile]
#pragma unroll
    for (int nt = 0; nt < 4; ++nt)
#pragma unroll
        for (int i = 0; i < 4; ++i) acc[nt][i] = (f4){0.f, 0.f, 0.f, 0.f};

#pragma unroll
    for (int kc = 0; kc < 4; ++kc) {
        int koff = kc * 32 + quad * 8;
        h8 a[4];
#pragma unroll
        for (int i = 0; i < 4; ++i)
            a[i] = *(const h8*)(Wt + (size_t)(ks * 64 + i * 16 + m16) * 128 + koff);
        h8 b[4];
#pragma unroll
        for (int nt = 0; nt < 4; ++nt) {
            int node = min(ntile + nt * 16 + m16, n - 1);
            b[nt] = *(const h8*)(Xh + (size_t)node * 128 + koff);
        }
#pragma unroll
        for (int nt = 0; nt < 4; ++nt)
#pragma unroll
            for (int i = 0; i < 4; ++i)
                acc[nt][i] = __builtin_amdgcn_mfma_f32_16x16x32_f16(a[i], b[nt], acc[nt][i], 0, 0, 0);
    }

#pragma unroll
    for (int nt = 0; nt < 4; ++nt) {
        int node = ntile + nt * 16 + m16;
        if (node < n) {
#pragma unroll
            for (int i = 0; i < 4; ++i) {
                int ob = i * 16 + quad * 4;        // out offset within slice
                f4 v = acc[nt][i];
                if (ks == 0) {
                    const f4 b4 = *(const f4*)(bias + ob);
                    v += b4;
                }
                half4 h;
                h.x = (half1)v[0]; h.y = (half1)v[1]; h.z = (half1)v[2]; h.w = (half1)v[3];
                *(half4*)(CB + ((size_t)ks * n + node) * 64 + ob) = h;
            }
        }
    }
}

// ---------------- small-layer GEMM: block = KK waves, wave k, lane = node -------------
template <int KK, int DIN4, int NACC>
__global__ void gemm_smallw_kernel(const float* __restrict__ X, const float* __restrict__ Wp,
                                   const float* __restrict__ bias, int dout,
                                   half4* __restrict__ CB, int n) {
    int lane = threadIdx.x & 63;
    int k = __builtin_amdgcn_readfirstlane((int)(threadIdx.x >> 6));
    int node0 = blockIdx.x * 64 + lane;
    int node = min(node0, n - 1);
    f4 acc[NACC];
#pragma unroll
    for (int i = 0; i < NACC; ++i) {
        f4 v = {0.f, 0.f, 0.f, 0.f};
        if (k == 0 && bias) {
#pragma unroll
            for (int c = 0; c < 4; ++c) {
                int o = i * 4 + c;
                v[c] = (o < dout) ? bias[o] : 0.f;
            }
        }
        acc[i] = v;
    }
    const f4* Xr = (const f4*)(X + (size_t)node * (DIN4 * 4));
    const f4* Wk = (const f4*)(Wp + (size_t)k * (DIN4 * 4) * (NACC * 4));
    for (int d4 = 0; d4 < DIN4; ++d4) {
        f4 xv = Xr[d4];
#pragma unroll
        for (int j = 0; j < 4; ++j) {
            float xs = xv[j];
#pragma unroll
            for (int i = 0; i < NACC; ++i)
                acc[i] += xs * Wk[(d4 * 4 + j) * NACC + i];
        }
    }
    if (node0 < n) {
        size_t base = ((size_t)k * n + node) * NACC;
#pragma unroll
        for (int i = 0; i < NACC; ++i) {
            half4 h;
            h.x = (half1)acc[i].x; h.y = (half1)acc[i].y;
            h.z = (half1)acc[i].z; h.w = (half1)acc[i].w;
            CB[base + i] = h;
        }
    }
}

// ---------------- host driver ----------------

extern "C" void kernel_launch(void* const* d_in, const int* in_sizes, int n_in,
                              void* d_out, int out_size, void* d_ws, size_t ws_size,
                              hipStream_t stream) {
    const float* x  = (const float*)d_in[0];
    const int*   ei = (const int*)d_in[1];
    const float* Wl[4] = {(const float*)d_in[2], (const float*)d_in[4],
                          (const float*)d_in[6], (const float*)d_in[8]};
    const float* bl[4] = {(const float*)d_in[3], (const float*)d_in[5],
                          (const float*)d_in[7], (const float*)d_in[9]};
    const float* bn[3][4];
    for (int l = 0; l < 3; ++l)
        for (int j = 0; j < 4; ++j)
            bn[l][j] = (const float*)d_in[10 + 4 * l + j];

    char* ws = (char*)d_ws;
    size_t off = 0;
    auto alloc = [&](size_t bytes) -> void* {
        void* p = (void*)(ws + off);
        off = (off + bytes + 255) & ~(size_t)255;
        return p;
    };
    int*   deg     = (int*)alloc(NN * 4);
    int*   row_ptr = (int*)alloc((NN + 1) * 4);
    int*   cursor  = (int*)alloc(NN * 4);
    int*   blks    = (int*)alloc(128 * 4);
    float* dinv    = (float*)alloc(NN * 4);
    int2*  cw      = (int2*)alloc((size_t)NE * 8);
    half1* CB1h    = (half1*)alloc((size_t)8 * NN * 64 * 2);
    half1* CBsh    = (half1*)alloc((size_t)6 * NN * 20 * 2);
    half1* S0      = (half1*)alloc((size_t)NN * 64 * 2);
    half1* S1      = (half1*)alloc((size_t)NN * 64 * 2);
    half1* S2      = (half1*)alloc((size_t)NN * 64 * 2);
    float* H1f     = (float*)alloc((size_t)NN * 64 * 4);
    float* H2f     = (float*)alloc((size_t)NN * 20 * 4);
    float* H3f     = (float*)alloc((size_t)NN * 12 * 4);
    float* Wp2     = (float*)alloc((size_t)6 * 64 * 20 * 4);
    float* Wp3     = (float*)alloc((size_t)4 * 20 * 12 * 4);
    float* Wp4     = (float*)alloc((size_t)4 * 12 * 12 * 4);
    half1* Xh      = (half1*)alloc((size_t)NN * 128 * 2);
    half1* Wt1     = (half1*)alloc((size_t)512 * 128 * 2);

    const int* srcp = ei;
    const int* dstp = ei + NE;
    const int nscan = divup(NN, 1024);
    const int NB = divup(NN, 64);

    hipMemsetAsync(deg, 0, NN * 4, stream);
    hipMemsetAsync(cursor, 0, NN * 4, stream);
    hist_kernel<<<divup(NE, 256), 256, 0, stream>>>(dstp, deg, NE);
    blksum_kernel<<<nscan, 256, 0, stream>>>(deg, blks, NN);
    blkscan_kernel<<<1, 256, 0, stream>>>(blks, nscan, row_ptr, NN);
    emit_kernel<<<nscan, 256, 0, stream>>>(deg, blks, row_ptr, NN);
    dinv_kernel<<<divup(NN, 256), 256, 0, stream>>>(deg, dinv, NN);
    scatter_kernel<<<divup(NE, 256), 256, 0, stream>>>(srcp, dstp, row_ptr, cursor, dinv, cw, NE);

    cvtx_kernel<<<divup(NN * 32, 256), 256, 0, stream>>>((const float4*)x, (half4*)Xh, NN * 32);
    transw_kernel<<<divup(512 * 128, 256), 256, 0, stream>>>(Wl[0], Wt1);
    padw_kernel<<<divup(6 * 64 * 20, 256), 256, 0, stream>>>(Wl[1], Wp2, 6, 64, 18, 64, 20);
    padw_kernel<<<divup(4 * 20 * 12, 256), 256, 0, stream>>>(Wl[2], Wp3, 4, 18, 9, 20, 12);
    padw_kernel<<<divup(4 * 12 * 12, 256), 256, 0, stream>>>(Wl[3], Wp4, 4, 9, 10, 12, 12);

    auto prop = [&](const half1* feat, const half1* sub, const half1* add,
                    half1* outh, float* outf, int dim4, float scale,
                    int bnrelu, int used, const float* g, const float* bb,
                    const float* m, const float* v) {
        proph_kernel<<<divup(NN * dim4, 256), 256, 0, stream>>>(
            (const half4*)feat, (const half4*)sub, (const half4*)add,
            (half4*)outh, (f4*)outf, row_ptr, cw, NN, dim4, scale,
            sub != nullptr, bnrelu, used, g, bb, m, v);
    };

    // ---- layer 1 (din=128, dout=64, K=8) -> H1f ----
    gemm_mfma_kernel<<<dim3(NB, 2), 256, 0, stream>>>(Xh, Wt1, bl[0], CB1h, NN);
    {
        auto C = [&](int k) { return (const half1*)(CB1h + (size_t)k * NN * 64); };
        prop(C(7), nullptr, C(6), S0, nullptr, 16, 2.f, 0, 64, 0, 0, 0, 0);
        prop(S0, C(7), C(5), S1, nullptr, 16, 2.f, 0, 64, 0, 0, 0, 0);
        prop(S1, S0, C(4), S2, nullptr, 16, 2.f, 0, 64, 0, 0, 0, 0);
        prop(S2, S1, C(3), S0, nullptr, 16, 2.f, 0, 64, 0, 0, 0, 0);
        prop(S0, S2, C(2), S1, nullptr, 16, 2.f, 0, 64, 0, 0, 0, 0);
        prop(S1, S0, C(1), S2, nullptr, 16, 2.f, 0, 64, 0, 0, 0, 0);
        prop(S2, S1, C(0), nullptr, H1f, 16, 1.f, 1, 64,
             bn[0][0], bn[0][1], bn[0][2], bn[0][3]);
    }

    // ---- layer 2 (din=64, dout=18 pad 20, K=6): X=H1f -> H2f ----
    gemm_smallw_kernel<6, 16, 5><<<NB, 384, 0, stream>>>(H1f, Wp2, bl[1], 18,
                                                         (half4*)CBsh, NN);
    {
        auto C = [&](int k) { return (const half1*)(CBsh + (size_t)k * NN * 20); };
        prop(C(5), nullptr, C(4), S0, nullptr, 5, 2.f, 0, 18, 0, 0, 0, 0);
        prop(S0, C(5), C(3), S1, nullptr, 5, 2.f, 0, 18, 0, 0, 0, 0);
        prop(S1, S0, C(2), S2, nullptr, 5, 2.f, 0, 18, 0, 0, 0, 0);
        prop(S2, S1, C(1), S0, nullptr, 5, 2.f, 0, 18, 0, 0, 0, 0);
        prop(S0, S2, C(0), nullptr, H2f, 5, 1.f, 1, 18,
             bn[1][0], bn[1][1], bn[1][2], bn[1][3]);
    }

    // ---- layer 3 (din=18 str20, dout=9 pad 12, K=4): X=H2f -> H3f ----
    gemm_smallw_kernel<4, 5, 3><<<NB, 256, 0, stream>>>(H2f, Wp3, bl[2], 9,
                                                        (half4*)CBsh, NN);
    {
        auto C = [&](int k) { return (const half1*)(CBsh + (size_t)k * NN * 12); };
        prop(C(3), nullptr, C(2), S0, nullptr, 3, 2.f, 0, 9, 0, 0, 0, 0);
        prop(S0, C(3), C(1), S1, nullptr, 3, 2.f, 0, 9, 0, 0, 0, 0);
        prop(S1, S0, C(0), nullptr, H3f, 3, 1.f, 1, 9,
             bn[2][0], bn[2][1], bn[2][2], bn[2][3]);
    }

    // ---- layer 4 (din=9 str12, dout=10 pad 12, K=4): X=H3f -> d_out ----
    gemm_smallw_kernel<4, 3, 3><<<NB, 256, 0, stream>>>(H3f, Wp4, bl[3], 10,
                                                        (half4*)CBsh, NN);
    {
        auto C = [&](int k) { return (const half1*)(CBsh + (size_t)k * NN * 12); };
        prop(C(3), nullptr, C(2), S0, nullptr, 3, 2.f, 0, 10, 0, 0, 0, 0);
        prop(S0, C(3), C(1), S1, nullptr, 3, 2.f, 0, 10, 0, 0, 0, 0);
        propl_kernel<<<divup(NN * 3, 256), 256, 0, stream>>>(
            (const half4*)S1, (const half4*)S0, (const half4*)CBsh,
            (float*)d_out, row_ptr, cw, NN);
    }
}